// Round 17
// baseline (626.573 us; speedup 1.0000x reference)
//
#include <hip/hip_runtime.h>
#include <math.h>

// OptionCompareCell: B=64,C=4,LO=64,LQ=128,H=768
// Round 17: GEMM K-step widened to BK=64 with 2 LDS buffers (64KB): halves the
//           barrier-step count (the ~365cyc/step fixed overhead identified from
//           r16's counters), same two-barrier counted-vmcnt invariants as
//           r12/r16. New both-sides swizzle for 64-col rows:
//           src seg = (l&7)^((l>>3)&7), read seg = (kk*4+l4)^(l15&7).
//           Everything else identical to round 16 (best = 599us).

#define NEGC (-10000.0f)
constexpr int HD = 768;
constexpr int KSTR = 9216;   // combined weight K-stride

constexpr int EP_TANH = 1;
constexpr int EP_MERGE = 2;
constexpr int EP_RELU = 3;
constexpr int EP_RELU_MAX = 4;

typedef __attribute__((ext_vector_type(8))) short bf16x8;
typedef __attribute__((ext_vector_type(8))) unsigned short u16x8;
typedef __attribute__((ext_vector_type(4))) unsigned short u16x4;
typedef __attribute__((ext_vector_type(4))) float f32x4;

__device__ inline void st8(float* dst, float4 a0, float4 a1) {
  dst[0] = a0.x; dst[1] = a0.y; dst[2] = a0.z; dst[3] = a0.w;
  dst[4] = a1.x; dst[5] = a1.y; dst[6] = a1.z; dst[7] = a1.w;
}

__device__ inline unsigned short f2bf(float x) {
  unsigned int u = __float_as_uint(x);
  u += 0x7fffu + ((u >> 16) & 1u);
  return (unsigned short)(u >> 16);
}

__device__ inline float bf2f(unsigned short u) {
  return __uint_as_float(((unsigned int)u) << 16);
}

__device__ inline u16x8 pack8(float4 a, float4 b) {
  u16x8 r;
  r[0] = f2bf(a.x); r[1] = f2bf(a.y); r[2] = f2bf(a.z); r[3] = f2bf(a.w);
  r[4] = f2bf(b.x); r[5] = f2bf(b.y); r[6] = f2bf(b.z); r[7] = f2bf(b.w);
  return r;
}

__device__ inline u16x4 pack4(float4 a) {
  u16x4 r;
  r[0] = f2bf(a.x); r[1] = f2bf(a.y); r[2] = f2bf(a.z); r[3] = f2bf(a.w);
  return r;
}

__device__ inline void gload_lds16(const unsigned short* src, unsigned short* dst) {
  __builtin_amdgcn_global_load_lds(
      (const __attribute__((address_space(1))) void*)src,
      (__attribute__((address_space(3))) void*)dst, 16, 0, 0);
}

// ---------------- fused enc_o prep: eobf, eow3, s1o, s2o in one pass ----------------
__global__ __launch_bounds__(256)
void bfprep_dot_kernel(const float* __restrict__ x, const float* __restrict__ w3,
                       const float* __restrict__ w1, const float* __restrict__ b1,
                       const float* __restrict__ w2, const float* __restrict__ b2,
                       unsigned short* __restrict__ xbf, unsigned short* __restrict__ xw3,
                       float* __restrict__ o1, float* __restrict__ o2, int ntok) {
  int tok = blockIdx.x * 4 + (threadIdx.x >> 6);
  int lane = threadIdx.x & 63;
  if (tok >= ntok) return;
  const float* xp = x + (size_t)tok * HD;
  unsigned short* xb = xbf + (size_t)tok * HD;
  unsigned short* xw = xw3 + (size_t)tok * HD;
  float s1 = 0.f, s2 = 0.f;
#pragma unroll
  for (int i = 0; i < 3; ++i) {
    int c = (lane + (i << 6)) << 2;
    float4 xv = *(const float4*)(xp + c);
    float4 w3v = *(const float4*)(w3 + c);
    float4 wa = *(const float4*)(w1 + c);
    float4 wb = *(const float4*)(w2 + c);
    s1 = fmaf(xv.x, wa.x, s1); s1 = fmaf(xv.y, wa.y, s1);
    s1 = fmaf(xv.z, wa.z, s1); s1 = fmaf(xv.w, wa.w, s1);
    s2 = fmaf(xv.x, wb.x, s2); s2 = fmaf(xv.y, wb.y, s2);
    s2 = fmaf(xv.z, wb.z, s2); s2 = fmaf(xv.w, wb.w, s2);
    *(u16x4*)(xb + c) = pack4(xv);
    float4 sv;
    sv.x = xv.x * w3v.x; sv.y = xv.y * w3v.y; sv.z = xv.z * w3v.z; sv.w = xv.w * w3v.w;
    *(u16x4*)(xw + c) = pack4(sv);
  }
#pragma unroll
  for (int off = 32; off; off >>= 1) {
    s1 += __shfl_xor(s1, off);
    s2 += __shfl_xor(s2, off);
  }
  if (lane == 0) { o1[tok] = s1 + b1[0]; o2[tok] = s2 + b2[0]; }
}

// ---------------- fused OPK prep: opkw3, sa1, sa2 in one pass ----------------
__global__ __launch_bounds__(256)
void opkprep_kernel(const unsigned short* __restrict__ x, const float* __restrict__ w3,
                    const float* __restrict__ w1, const float* __restrict__ b1,
                    const float* __restrict__ w2, const float* __restrict__ b2,
                    unsigned short* __restrict__ xw3,
                    float* __restrict__ o1, float* __restrict__ o2, int ntok) {
  int tok = blockIdx.x * 4 + (threadIdx.x >> 6);
  int lane = threadIdx.x & 63;
  if (tok >= ntok) return;
  const unsigned short* xp = x + (size_t)tok * HD;
  unsigned short* xw = xw3 + (size_t)tok * HD;
  float s1 = 0.f, s2 = 0.f;
#pragma unroll
  for (int i = 0; i < 3; ++i) {
    int c = (lane + (i << 6)) << 2;
    u16x4 xv = *(const u16x4*)(xp + c);
    float x0 = bf2f(xv[0]), x1 = bf2f(xv[1]), x2 = bf2f(xv[2]), x3 = bf2f(xv[3]);
    float4 w3v = *(const float4*)(w3 + c);
    float4 wa = *(const float4*)(w1 + c);
    float4 wb = *(const float4*)(w2 + c);
    s1 = fmaf(x0, wa.x, s1); s1 = fmaf(x1, wa.y, s1);
    s1 = fmaf(x2, wa.z, s1); s1 = fmaf(x3, wa.w, s1);
    s2 = fmaf(x0, wb.x, s2); s2 = fmaf(x1, wb.y, s2);
    s2 = fmaf(x2, wb.z, s2); s2 = fmaf(x3, wb.w, s2);
    u16x4 sv;
    sv[0] = f2bf(x0 * w3v.x); sv[1] = f2bf(x1 * w3v.y);
    sv[2] = f2bf(x2 * w3v.z); sv[3] = f2bf(x3 * w3v.w);
    *(u16x4*)(xw + c) = sv;
  }
#pragma unroll
  for (int off = 32; off; off >>= 1) {
    s1 += __shfl_xor(s1, off);
    s2 += __shfl_xor(s2, off);
  }
  if (lane == 0) { o1[tok] = s1 + b1[0]; o2[tok] = s2 + b2[0]; }
}

// ---- qpool2: per bc, fused Va/co_W1 dots + masked softmax + pooled Q ----
__global__ __launch_bounds__(256)
void qpool2_kernel(const float* __restrict__ q,
                   const float* __restrict__ Va_w, const float* __restrict__ Va_b,
                   const float* __restrict__ coW1_w, const float* __restrict__ coW1_b,
                   const int* __restrict__ qm,
                   float* __restrict__ qco1, float* __restrict__ Q) {
  __shared__ float qa_s[128];
  __shared__ float wgt[128];
  __shared__ float wred[4];
  const int t = threadIdx.x, bc = blockIdx.x;
  const int lane = t & 63, wv = t >> 6;
  const float* qb = q + (size_t)bc * (128 * HD);
  for (int it = 0; it < 32; ++it) {
    const int tl = it * 4 + wv;
    const float* xp = qb + (size_t)tl * HD;
    float s1 = 0.f, s2 = 0.f;
#pragma unroll
    for (int i = 0; i < 3; ++i) {
      int c = (lane + (i << 6)) << 2;
      float4 xv = *(const float4*)(xp + c);
      float4 wa = *(const float4*)(Va_w + c);
      float4 wb = *(const float4*)(coW1_w + c);
      s1 = fmaf(xv.x, wa.x, s1); s1 = fmaf(xv.y, wa.y, s1);
      s1 = fmaf(xv.z, wa.z, s1); s1 = fmaf(xv.w, wa.w, s1);
      s2 = fmaf(xv.x, wb.x, s2); s2 = fmaf(xv.y, wb.y, s2);
      s2 = fmaf(xv.z, wb.z, s2); s2 = fmaf(xv.w, wb.w, s2);
    }
#pragma unroll
    for (int off = 32; off; off >>= 1) {
      s1 += __shfl_xor(s1, off);
      s2 += __shfl_xor(s2, off);
    }
    if (lane == 0) {
      qa_s[tl] = s1 + Va_b[0];
      qco1[bc * 128 + tl] = s2 + coW1_b[0];
    }
  }
  __syncthreads();
  const int* qmp = qm + bc * 128;
  float v = -1e30f;
  if (t < 128) v = qa_s[t] + (1.f - (float)qmp[t]) * NEGC;
  float m = v;
#pragma unroll
  for (int off = 32; off; off >>= 1) m = fmaxf(m, __shfl_xor(m, off));
  if ((t & 63) == 0) wred[t >> 6] = m;
  __syncthreads();
  float gm = fmaxf(fmaxf(wred[0], wred[1]), fmaxf(wred[2], wred[3]));
  float e = (t < 128) ? expf(v - gm) : 0.f;
  float s = e;
#pragma unroll
  for (int off = 32; off; off >>= 1) s += __shfl_xor(s, off);
  __syncthreads();
  if ((t & 63) == 0) wred[t >> 6] = s;
  __syncthreads();
  float tot = wred[0] + wred[1] + wred[2] + wred[3];
  if (t < 128) wgt[t] = e / tot;
  __syncthreads();
  float* Qp = Q + (size_t)bc * HD;
  for (int d = t; d < HD; d += 256) {
    float acc = 0.f;
    for (int l = 0; l < 128; ++l) acc = fmaf(wgt[l], qb[(size_t)l * HD + d], acc);
    Qp[d] = acc;
  }
}

// ---------------- P1: S = U . Vw3^T (MFMA), softmax over u, write Pt[v][u] bf16 ----------------
template<int NJ>
__global__ __launch_bounds__(256)
void p1_kernel(const unsigned short* __restrict__ Xbf, const unsigned short* __restrict__ Xw3,
               const float* __restrict__ s1g, const float* __restrict__ s2g,
               const int* __restrict__ maskg, unsigned short* __restrict__ PtG) {
  __shared__ __align__(16) unsigned short Ua[64 * 136];
  __shared__ __align__(16) unsigned short Vb[64 * 136];
  __shared__ float Sbuf[64][66];
  __shared__ float red[4][64];
  const int t = threadIdx.x;
  int ubc, vbc;
  if (NJ == 1) {
    ubc = vbc = blockIdx.x;
  } else {
    const int b = blockIdx.x / 12, pr = blockIdx.x % 12;
    const int i = pr / 3, jj = pr % 3;
    const int j = jj + (jj >= i ? 1 : 0);
    vbc = (b << 2) + i; ubc = (b << 2) + j;
  }
  const unsigned short* U = Xbf + (size_t)ubc * (64 * HD);
  const unsigned short* V = Xw3 + (size_t)vbc * (64 * HD);
  const int w = t >> 6, lane = t & 63, l15 = lane & 15, l4 = lane >> 4;
  const int srow = t >> 2, scol = (t & 3) << 5;
  f32x4 acc[4] = {};
  for (int k0 = 0; k0 < HD; k0 += 128) {
    const unsigned short* up = U + (size_t)srow * HD + k0 + scol;
    const unsigned short* vp = V + (size_t)srow * HD + k0 + scol;
    unsigned short* ua = &Ua[srow * 136 + scol];
    unsigned short* vb = &Vb[srow * 136 + scol];
#pragma unroll
    for (int z = 0; z < 4; ++z) {
      *(u16x8*)(ua + z * 8) = *(const u16x8*)(up + z * 8);
      *(u16x8*)(vb + z * 8) = *(const u16x8*)(vp + z * 8);
    }
    __syncthreads();
#pragma unroll
    for (int ks = 0; ks < 4; ++ks) {
      bf16x8 af = *(const bf16x8*)(&Ua[(w * 16 + l15) * 136 + ks * 32 + l4 * 8]);
#pragma unroll
      for (int n = 0; n < 4; ++n) {
        bf16x8 bf = *(const bf16x8*)(&Vb[(n * 16 + l15) * 136 + ks * 32 + l4 * 8]);
        acc[n] = __builtin_amdgcn_mfma_f32_16x16x32_bf16(af, bf, acc[n], 0, 0, 0);
      }
    }
    __syncthreads();
  }
  {
    float s1v[4];
#pragma unroll
    for (int r = 0; r < 4; ++r) {
      int u = w * 16 + l4 * 4 + r;
      s1v[r] = s1g[ubc * 64 + u] + (1.f - (float)maskg[ubc * 64 + u]) * NEGC;
    }
#pragma unroll
    for (int n = 0; n < 4; ++n) {
      int v = n * 16 + l15;
      float s2v = s2g[vbc * 64 + v] + (1.f - (float)maskg[vbc * 64 + v]) * NEGC;
#pragma unroll
      for (int r = 0; r < 4; ++r)
        Sbuf[w * 16 + l4 * 4 + r][v] = acc[n][r] + s1v[r] + s2v;
    }
  }
  __syncthreads();
  {
    const int v = t & 63, part = t >> 6;
    float m = -1e30f;
#pragma unroll
    for (int z = 0; z < 16; ++z) m = fmaxf(m, Sbuf[part * 16 + z][v]);
    red[part][v] = m;
    __syncthreads();
    float gm = fmaxf(fmaxf(red[0][v], red[1][v]), fmaxf(red[2][v], red[3][v]));
    float s = 0.f;
#pragma unroll
    for (int z = 0; z < 16; ++z) {
      float e = expf(Sbuf[part * 16 + z][v] - gm);
      Sbuf[part * 16 + z][v] = e;
      s += e;
    }
    __syncthreads();
    red[part][v] = s;
    __syncthreads();
    float cinv = 1.f / (red[0][v] + red[1][v] + red[2][v] + red[3][v]);
    unsigned short* pt = PtG + (size_t)blockIdx.x * 4096 + v * 64 + part * 16;
#pragma unroll
    for (int z = 0; z < 16; ++z) pt[z] = f2bf(Sbuf[part * 16 + z][v] * cinv);
  }
}

// ---- P2: ctx = sum_j Pt_j . U_j ; fused epilogue: NJ=3 -> X1,X2 ; NJ=1 -> OSK,X3,X4 ----
template<int NJ>
__global__ __launch_bounds__(256)
void p2_kernel(const unsigned short* __restrict__ Xbf, const unsigned short* __restrict__ PtG,
               const unsigned short* __restrict__ Oi,
               unsigned short* __restrict__ osk,
               unsigned short* __restrict__ y1, unsigned short* __restrict__ y2) {
  __shared__ __align__(16) unsigned short Pts[NJ][64 * 72];
  __shared__ __align__(16) unsigned short U2[64 * 192];
  const int t = threadIdx.x;
  const int dq = blockIdx.x, bc = blockIdx.y;
  const int d0 = dq * 192;
  const int b = bc >> 2, i = bc & 3;
  const int w = t >> 6, lane = t & 63, l15 = lane & 15, l4 = lane >> 4;
  {
    const int v = t >> 2, cs = (t & 3) << 4;
#pragma unroll
    for (int jj = 0; jj < NJ; ++jj) {
      size_t src = (NJ == 1 ? (size_t)bc : (size_t)(b * 12 + i * 3 + jj)) * 4096 + v * 64 + cs;
      *(u16x8*)(&Pts[jj][v * 72 + cs]) = *(const u16x8*)(PtG + src);
      *(u16x8*)(&Pts[jj][v * 72 + cs + 8]) = *(const u16x8*)(PtG + src + 8);
    }
  }
  f32x4 acc[4][3] = {};
  const int su = t >> 2, sc0 = (t & 3) * 48;
  const int sswz = ((su >> 3) & 3) << 5;
  for (int jj = 0; jj < NJ; ++jj) {
    const int ubc = (NJ == 1) ? bc : ((b << 2) + (jj + (jj >= i ? 1 : 0)));
    __syncthreads();
    {
      const unsigned short* up = Xbf + (size_t)ubc * (64 * HD) + (size_t)su * HD + d0 + sc0;
#pragma unroll
      for (int it = 0; it < 6; ++it) {
        u16x8 vdat = *(const u16x8*)(up + it * 8);
        *(u16x8*)((char*)U2 + ((su * 384 + (sc0 + it * 8) * 2) ^ sswz)) = vdat;
      }
    }
    __syncthreads();
    const unsigned short* ptj = &Pts[jj][0];
#pragma unroll
    for (int ks = 0; ks < 2; ++ks) {
      bf16x8 bfr[3];
#pragma unroll
      for (int n = 0; n < 3; ++n) {
        const int col = (w * 3 + n) * 16 + l15;
#pragma unroll
        for (int e = 0; e < 8; ++e) {
          const int uk = ks * 32 + l4 * 8 + e;
          const int byte = (uk * 384 + col * 2) ^ (((uk >> 3) & 3) << 5);
          bfr[n][e] = *(const short*)((const char*)U2 + byte);
        }
      }
#pragma unroll
      for (int m = 0; m < 4; ++m) {
        bf16x8 af = *(const bf16x8*)(ptj + (m * 16 + l15) * 72 + ks * 32 + l4 * 8);
#pragma unroll
        for (int n = 0; n < 3; ++n)
          acc[m][n] = __builtin_amdgcn_mfma_f32_16x16x32_bf16(af, bfr[n], acc[m][n], 0, 0, 0);
      }
    }
  }
  const unsigned short* oip = Oi + (size_t)bc * (64 * HD);
  const size_t obase = (size_t)bc * (64 * HD);
#pragma unroll
  for (int m = 0; m < 4; ++m)
#pragma unroll
    for (int n = 0; n < 3; ++n) {
      const int d = d0 + (w * 3 + n) * 16 + l15;
#pragma unroll
      for (int r = 0; r < 4; ++r) {
        const int v = m * 16 + l4 * 4 + r;
        const size_t idx = obase + (size_t)v * HD + d;
        const float cs = acc[m][n][r];
        const float oi = bf2f(oip[(size_t)v * HD + d]);
        if (NJ == 3) {
          y1[idx] = f2bf(fmaf(3.f, oi, -cs));
          y2[idx] = f2bf(oi * cs);
        } else {
          osk[idx] = f2bf(cs);
          y1[idx] = f2bf(oi - cs);
          y2[idx] = f2bf(oi * cs);
        }
      }
    }
}

// ---- POAA fused with A2 + ms2 (computed during Bm staging) ----
__global__ __launch_bounds__(256)
void poaa2_kernel(const float* __restrict__ qin, const unsigned short* __restrict__ mergedb,
                  const float* __restrict__ qco1,
                  const float* __restrict__ coW2_w, const float* __restrict__ coW2_b,
                  const int* __restrict__ qm, const int* __restrict__ om,
                  const float* __restrict__ w3,
                  unsigned short* __restrict__ PLO, unsigned short* __restrict__ PHI) {
  __shared__ __align__(16) char smem[77312];
  __shared__ float red[4][64];
  __shared__ float rowm[128], rowfac[128];
  __shared__ float colfac[64];
  __shared__ float ms2_s[64];
  __shared__ float gmax_s;
  float* T = (float*)smem;                                   // [128][65] f32
  unsigned short* Aq = (unsigned short*)smem;                 // [128][72] (phase0)
  unsigned short* Bm = (unsigned short*)(smem + 18432);       // [64][72]  (phase0)
  unsigned short* Tt = (unsigned short*)(smem + 33280);       // [64][136]
  unsigned short* Tft = (unsigned short*)(smem + 50688);      // [64][136]
  unsigned short* M2bf = (unsigned short*)(smem + 68096);     // [64][72]
  unsigned short* Qc = (unsigned short*)smem;                 // [128][72] (chunk phase)
  unsigned short* Mc = (unsigned short*)(smem + 18432);       // [64][72]

  const int t = threadIdx.x, dqh = blockIdx.x, bc = blockIdx.y;
  const int w = t >> 6, lane = t & 63, l15 = lane & 15, l4 = lane >> 4;
  const float* qp = qin + (size_t)bc * (128 * HD);
  const unsigned short* mp = mergedb + (size_t)bc * (64 * HD);
  const float* qc = qco1 + bc * 128;
  const int* qmp = qm + bc * 128;
  const int* omp = om + bc * 64;

  // ---- phase 0: A2 = (q*w3).merged^T via MFMA ; ms2 dot rides the Bm staging ----
  {
    const int arow = t >> 1, acs = (t & 1) << 5;
    const int brow = t >> 2, bcs = (t & 3) << 4;
    f32x4 acc[2][4] = {};
    float msacc = 0.f;
    for (int k0 = 0; k0 < HD; k0 += 64) {
      {
        const float* p = qp + (size_t)arow * HD + k0 + acs;
        const float* wp = w3 + k0 + acs;
        unsigned short* dst = &Aq[arow * 72 + acs];
#pragma unroll
        for (int z = 0; z < 4; ++z) {
          float4 a = *(const float4*)(p + z * 8);
          float4 b = *(const float4*)(p + z * 8 + 4);
          float4 wa = *(const float4*)(wp + z * 8);
          float4 wb = *(const float4*)(wp + z * 8 + 4);
          a.x *= wa.x; a.y *= wa.y; a.z *= wa.z; a.w *= wa.w;
          b.x *= wb.x; b.y *= wb.y; b.z *= wb.z; b.w *= wb.w;
          *(u16x8*)(dst + z * 8) = pack8(a, b);
        }
      }
      {
        const unsigned short* p = mp + (size_t)brow * HD + k0 + bcs;
        unsigned short* dst = &Bm[brow * 72 + bcs];
        u16x8 v0 = *(const u16x8*)(p);
        u16x8 v1 = *(const u16x8*)(p + 8);
        *(u16x8*)(dst) = v0;
        *(u16x8*)(dst + 8) = v1;
        const float* wp = coW2_w + k0 + bcs;
        float4 wa = *(const float4*)(wp);
        float4 wb = *(const float4*)(wp + 4);
        float4 wc = *(const float4*)(wp + 8);
        float4 wd = *(const float4*)(wp + 12);
        msacc = fmaf(bf2f(v0[0]), wa.x, msacc); msacc = fmaf(bf2f(v0[1]), wa.y, msacc);
        msacc = fmaf(bf2f(v0[2]), wa.z, msacc); msacc = fmaf(bf2f(v0[3]), wa.w, msacc);
        msacc = fmaf(bf2f(v0[4]), wb.x, msacc); msacc = fmaf(bf2f(v0[5]), wb.y, msacc);
        msacc = fmaf(bf2f(v0[6]), wb.z, msacc); msacc = fmaf(bf2f(v0[7]), wb.w, msacc);
        msacc = fmaf(bf2f(v1[0]), wc.x, msacc); msacc = fmaf(bf2f(v1[1]), wc.y, msacc);
        msacc = fmaf(bf2f(v1[2]), wc.z, msacc); msacc = fmaf(bf2f(v1[3]), wc.w, msacc);
        msacc = fmaf(bf2f(v1[4]), wd.x, msacc); msacc = fmaf(bf2f(v1[5]), wd.y, msacc);
        msacc = fmaf(bf2f(v1[6]), wd.z, msacc); msacc = fmaf(bf2f(v1[7]), wd.w, msacc);
      }
      __syncthreads();
#pragma unroll
      for (int ks = 0; ks < 2; ++ks) {
        bf16x8 af[2], bf[4];
#pragma unroll
        for (int m = 0; m < 2; ++m)
          af[m] = *(const bf16x8*)(&Aq[(w * 32 + m * 16 + l15) * 72 + ks * 32 + l4 * 8]);
#pragma unroll
        for (int n = 0; n < 4; ++n)
          bf[n] = *(const bf16x8*)(&Bm[(n * 16 + l15) * 72 + ks * 32 + l4 * 8]);
#pragma unroll
        for (int m = 0; m < 2; ++m)
#pragma unroll
          for (int n = 0; n < 4; ++n)
            acc[m][n] = __builtin_amdgcn_mfma_f32_16x16x32_bf16(af[m], bf[n], acc[m][n], 0, 0, 0);
      }
      __syncthreads();
    }
    msacc += __shfl_xor(msacc, 1);
    msacc += __shfl_xor(msacc, 2);
    if ((t & 3) == 0) ms2_s[brow] = msacc + coW2_b[0];
    __syncthreads();
#pragma unroll
    for (int n = 0; n < 4; ++n) {
      const int v = n * 16 + l15;
      const float ct = ms2_s[v] + (1.f - (float)omp[v]) * NEGC;
#pragma unroll
      for (int m = 0; m < 2; ++m)
#pragma unroll
        for (int r = 0; r < 4; ++r) {
          const int qrow = w * 32 + m * 16 + l4 * 4 + r;
          const float rt = qc[qrow] + (1.f - (float)qmp[qrow]) * NEGC;
          T[qrow * 65 + v] = acc[m][n][r] + rt + ct;
        }
    }
  }
  __syncthreads();
  // ---- stats ----
  {
    int qrow = t >> 1, h = t & 1;
    float m = -1e30f;
    for (int v = h * 32; v < h * 32 + 32; ++v) m = fmaxf(m, T[qrow * 65 + v]);
    m = fmaxf(m, __shfl_xor(m, 1));
    float s = 0.f;
    for (int v = h * 32; v < h * 32 + 32; ++v) s += expf(T[qrow * 65 + v] - m);
    s += __shfl_xor(s, 1);
    if (h == 0) { rowm[qrow] = m; rowfac[qrow] = s; }
  }
  float colm_loc = 0.f;
  {
    int v = t & 63, part = t >> 6;
    float m = -1e30f;
    for (int qq = part * 32; qq < part * 32 + 32; ++qq) m = fmaxf(m, T[qq * 65 + v]);
    red[part][v] = m;
    __syncthreads();
    float cm = fmaxf(fmaxf(red[0][v], red[1][v]), fmaxf(red[2][v], red[3][v]));
    float s = 0.f;
    for (int qq = part * 32; qq < part * 32 + 32; ++qq) s += expf(T[qq * 65 + v] - cm);
    __syncthreads();
    red[part][v] = s;
    __syncthreads();
    if (part == 0) { colm_loc = cm; colfac[v] = red[0][v] + red[1][v] + red[2][v] + red[3][v]; }
  }
  __syncthreads();
  if (t < 64) {
    float m = fmaxf(rowm[t], rowm[t + 64]);
#pragma unroll
    for (int off = 32; off; off >>= 1) m = fmaxf(m, __shfl_xor(m, off));
    if (t == 0) gmax_s = m;
  }
  __syncthreads();
  const float gmax = gmax_s;
  if (t < 128) rowfac[t] = expf(fminf(gmax - rowm[t], 60.f)) / rowfac[t];
  if (t < 64) colfac[t] = expf(fminf(gmax - colm_loc, 60.f)) / colfac[t];
  __syncthreads();
  {
    const int o = t >> 2, qs = (t & 3) << 5;
    for (int z = 0; z < 32; ++z) {
      const int qq = qs + z;
      float e = expf(T[qq * 65 + o] - gmax);
      Tt[o * 136 + qq] = f2bf(e);
      Tft[o * 136 + qq] = f2bf(e * rowfac[qq]);
    }
  }
  __syncthreads();
  {
    f32x4 m2acc[4] = {};
#pragma unroll
    for (int ks = 0; ks < 4; ++ks) {
      bf16x8 af = *(const bf16x8*)(&Tt[(w * 16 + l15) * 136 + ks * 32 + l4 * 8]);
#pragma unroll
      for (int n = 0; n < 4; ++n) {
        bf16x8 bf = *(const bf16x8*)(&Tft[(n * 16 + l15) * 136 + ks * 32 + l4 * 8]);
        m2acc[n] = __builtin_amdgcn_mfma_f32_16x16x32_bf16(af, bf, m2acc[n], 0, 0, 0);
      }
    }
#pragma unroll
    for (int n = 0; n < 4; ++n)
#pragma unroll
      for (int r = 0; r < 4; ++r) {
        const int o = w * 16 + l4 * 4 + r;
        M2bf[o * 72 + n * 16 + l15] = f2bf(colfac[o] * m2acc[n][r]);
      }
  }
  // ---- chunk phase (d-half dqh) ----
  const int dql = t >> 1, dqs = (t & 1) << 5;
  const int dml = t >> 2, dms = (t & 3) << 4;
  const int swq = ((dql >> 3) & 3) << 5;
  const int swm = ((dml >> 3) & 3) << 5;
  unsigned short* plo = PLO + (size_t)bc * (64 * HD);
  unsigned short* phi = PHI + (size_t)bc * (64 * HD);
  for (int dc = dqh * 6; dc < dqh * 6 + 6; ++dc) {
    const int d0 = dc * 64;
    __syncthreads();
    {
      const float* p = qp + (size_t)dql * HD + d0 + dqs;
#pragma unroll
      for (int z = 0; z < 4; ++z) {
        float4 a = *(const float4*)(p + z * 8);
        float4 b = *(const float4*)(p + z * 8 + 4);
        *(u16x8*)((char*)Qc + ((dql * 144 + (dqs + z * 8) * 2) ^ swq)) = pack8(a, b);
      }
    }
    {
      const unsigned short* p = mp + (size_t)dml * HD + d0 + dms;
      *(u16x8*)((char*)Mc + ((dml * 144 + dms * 2) ^ swm)) = *(const u16x8*)p;
      *(u16x8*)((char*)Mc + ((dml * 144 + (dms + 8) * 2) ^ swm)) = *(const u16x8*)(p + 8);
    }
    __syncthreads();
    const int col = w * 16 + l15;
    f32x4 lacc[4] = {};
#pragma unroll
    for (int ks = 0; ks < 4; ++ks) {
      bf16x8 bf;
#pragma unroll
      for (int e = 0; e < 8; ++e) {
        const int qq = ks * 32 + l4 * 8 + e;
        bf[e] = *(const short*)((const char*)Qc + ((qq * 144 + col * 2) ^ (((qq >> 3) & 3) << 5)));
      }
#pragma unroll
      for (int m = 0; m < 4; ++m) {
        bf16x8 af = *(const bf16x8*)(&Tt[(m * 16 + l15) * 136 + ks * 32 + l4 * 8]);
        lacc[m] = __builtin_amdgcn_mfma_f32_16x16x32_bf16(af, bf, lacc[m], 0, 0, 0);
      }
    }
    f32x4 pacc[4] = {};
#pragma unroll
    for (int ks = 0; ks < 2; ++ks) {
      bf16x8 bf;
#pragma unroll
      for (int e = 0; e < 8; ++e) {
        const int vv = ks * 32 + l4 * 8 + e;
        bf[e] = *(const short*)((const char*)Mc + ((vv * 144 + col * 2) ^ (((vv >> 3) & 3) << 5)));
      }
#pragma unroll
      for (int m = 0; m < 4; ++m) {
        bf16x8 af = *(const bf16x8*)(&M2bf[(m * 16 + l15) * 72 + ks * 32 + l4 * 8]);
        pacc[m] = __builtin_amdgcn_mfma_f32_16x16x32_bf16(af, bf, pacc[m], 0, 0, 0);
      }
    }
#pragma unroll
    for (int m = 0; m < 4; ++m)
#pragma unroll
      for (int r = 0; r < 4; ++r) {
        const int o = m * 16 + l4 * 4 + r;
        const int d = d0 + w * 16 + l15;
        plo[(size_t)o * HD + d] = f2bf(colfac[o] * lacc[m][r]);
        phi[(size_t)o * HD + d] = f2bf(pacc[m][r]);
      }
  }
}

// ---------------- small f32 GEMM (Qg only) ----------------
struct GemmArgs {
  const float* a[4];
  const float* w[4];
  int nchunks;
  const float* bias;
  float* out;
};

__global__ __launch_bounds__(256)
void gemm_store_kernel(GemmArgs g) {
  __shared__ float As[64][33];
  __shared__ float Ws[32][65];
  const int t = threadIdx.x;
  const int m0 = blockIdx.y << 6, n0 = blockIdx.x << 6;
  const int tr = t >> 4, tc = t & 15;
  float acc[4][4];
#pragma unroll
  for (int x = 0; x < 4; ++x)
#pragma unroll
    for (int y = 0; y < 4; ++y) acc[x][y] = 0.f;
  const int arow = t >> 2, acs = (t & 3) << 3;
  const int wrow = t >> 3, wcs = (t & 7) << 3;
  for (int c = 0; c < g.nchunks; ++c) {
    const float* Ap = g.a[c] + (size_t)(m0 + arow) * HD + acs;
    const float* Wp = g.w[c] + (size_t)wrow * HD + n0 + wcs;
    for (int k0 = 0; k0 < HD; k0 += 32) {
      float4 a0 = *(const float4*)(Ap + k0);
      float4 a1 = *(const float4*)(Ap + k0 + 4);
      st8(&As[arow][acs], a0, a1);
      float4 w0 = *(const float4*)(Wp + (size_t)k0 * HD);
      float4 w1 = *(const float4*)(Wp + (size_t)k0 * HD + 4);
      st8(&Ws[wrow][wcs], w0, w1);
      __syncthreads();
#pragma unroll
      for (int kk = 0; kk < 32; ++kk) {
        float av[4], bv[4];
#pragma unroll
        for (int x = 0; x < 4; ++x) av[x] = As[(tr << 2) + x][kk];
#pragma unroll
        for (int y = 0; y < 4; ++y) bv[y] = Ws[kk][(tc << 2) + y];
#pragma unroll
        for (int x = 0; x < 4; ++x)
#pragma unroll
          for (int y = 0; y < 4; ++y) acc[x][y] = fmaf(av[x], bv[y], acc[x][y]);
      }
      __syncthreads();
    }
  }
#pragma unroll
  for (int x = 0; x < 4; ++x) {
    const int r = m0 + (tr << 2) + x;
#pragma unroll
    for (int y = 0; y < 4; ++y) {
      const int n = n0 + (tc << 2) + y;
      g.out[(size_t)r * HD + n] = acc[x][y] + g.bias[n];
    }
  }
}

// ---------------- wconv_all: 12 weight slices -> wall[768][9216] bf16 ----------------
struct WcAllArgs {
  const float* src[12];
  int basecol[12];
  unsigned short* dst;
};

__global__ __launch_bounds__(256)
void wconv_all_kernel(WcAllArgs g) {
  __shared__ float tile[64][65];
  const int slice = blockIdx.y;
  const float* src = g.src[slice];
  const int bi = blockIdx.x % 12, bj = blockIdx.x / 12;
  const int t = threadIdx.x;
  const int r = t >> 2, cseg = (t & 3) << 4;
  const float* p = src + (size_t)(bi * 64 + r) * HD + bj * 64 + cseg;
#pragma unroll
  for (int j = 0; j < 16; j += 4) {
    float4 v = *(const float4*)(p + j);
    tile[r][cseg + j + 0] = v.x; tile[r][cseg + j + 1] = v.y;
    tile[r][cseg + j + 2] = v.z; tile[r][cseg + j + 3] = v.w;
  }
  __syncthreads();
  unsigned short* q = g.dst + (size_t)(bj * 64 + r) * KSTR + g.basecol[slice] + bi * 64 + cseg;
  u16x8 lo, hi;
#pragma unroll
  for (int j = 0; j < 8; ++j) lo[j] = f2bf(tile[cseg + j][r]);
#pragma unroll
  for (int j = 0; j < 8; ++j) hi[j] = f2bf(tile[cseg + 8 + j][r]);
  *(u16x8*)q = lo;
  *(u16x8*)(q + 8) = hi;
}

// ---- bf16 MFMA GEMM: 8-wave, BK=64, 2-buffer two-barrier counted-vmcnt ----
struct MMArgs {
  const unsigned short* a[4];   // per-768-chunk bf16 sources (all mode-0)
  int K;
  const unsigned short* wt;     // wall + basecol, row stride KSTR
  const float* bias;
  const float* bias2;           // EP_TANH: bias + 3*bias2
  const unsigned short* aux0;   // o1 bf16  (EP_MERGE)
  const unsigned short* aux1;   // OCK bf16 (EP_MERGE)
  const float* aux2;            // Qg f32   (EP_MERGE)
  float* outf;                  // EP_RELU_MAX
  unsigned short* outb;         // others
};

template<int EP>
__global__ __launch_bounds__(512)
void mfma_gemm_kernel(MMArgs g) {
  // tiles are [128 rows][64 shorts]; per buffer A(16KB)+B(16KB); 2 buffers = 64KB
  __shared__ __align__(16) unsigned short As[2][128 * 64];
  __shared__ __align__(16) unsigned short Bs[2][128 * 64];
  const int t = threadIdx.x;
  const int lane = t & 63, w = t >> 6;       // 8 waves
  const int wr = w >> 2, wc = w & 3;          // 2 x 4 decomposition
  const int m0 = blockIdx.x << 7, n0 = blockIdx.y << 7;  // m-fast grid
  const int l15 = lane & 15, l4 = lane >> 4;
  f32x4 acc[4][2] = {};

  // staging: wave w covers rows w*16..w*16+15; 2 issues per matrix, each issue
  // covers 8 rows x 64 shorts (1KB linear). Source col pre-swizzled so that
  // LDS[row][seg] holds global seg (seg ^ (row&7)); read applies the same XOR.
  const int gseg = ((lane & 7) ^ ((lane >> 3) & 7)) * 8;     // shorts (src col)
  const int irow = lane >> 3;                                 // 0..7 within issue

  const int nkt = g.K >> 6;   // BK=64 tiles

  auto issue = [&](int kt, int buf) {
    const int c = kt / 12;                    // 768/64 = 12 tiles per chunk
    const int koff = (kt - c * 12) << 6;
#pragma unroll
    for (int i = 0; i < 2; ++i) {
      const int grow = w * 16 + i * 8 + irow;
      const unsigned short* ap = g.a[c] + (size_t)(m0 + grow) * HD + koff + gseg;
      const unsigned short* bp = g.wt + (size_t)(n0 + grow) * KSTR + (kt << 6) + gseg;
      gload_lds16(ap, &As[buf][w * 1024 + i * 512]);
      gload_lds16(bp, &Bs[buf][w * 1024 + i * 512]);
    }
  };

  auto compute = [&](int kt, int buf, bool prefetch) {
    // frag reads for both K-halves up front (swizzled segs), then barrier+issue+MFMA
    bf16x8 af[2][4], bfr[2][2];
#pragma unroll
    for (int kk = 0; kk < 2; ++kk) {
#pragma unroll
      for (int mi = 0; mi < 4; ++mi) {
        const int row = wr * 64 + mi * 16 + l15;
        const int seg = (kk * 4 + l4) ^ (l15 & 7);
        af[kk][mi] = *(const bf16x8*)(&As[buf][row * 64 + seg * 8]);
      }
#pragma unroll
      for (int ni = 0; ni < 2; ++ni) {
        const int row = wc * 32 + ni * 16 + l15;
        const int seg = (kk * 4 + l4) ^ (l15 & 7);
        bfr[kk][ni] = *(const bf16x8*)(&Bs[buf][row * 64 + seg * 8]);
      }
    }
    asm volatile("s_waitcnt lgkmcnt(0)" ::: "memory");  // my frags in regs
    __builtin_amdgcn_s_barrier();                        // everyone done reading buf
    if (prefetch) issue(kt + 2, buf);                    // safe to overwrite now
    __builtin_amdgcn_s_setprio(1);
#pragma unroll
    for (int kk = 0; kk < 2; ++kk)
#pragma unroll
      for (int mi = 0; mi < 4; ++mi)
#pragma unroll
        for (int ni = 0; ni < 2; ++ni)
          acc[mi][ni] = __builtin_amdgcn_mfma_f32_16x16x32_bf16(af[kk][mi], bfr[kk][ni], acc[mi][ni], 0, 0, 0);
    __builtin_amdgcn_s_setprio(0);
  };

  // prologue: 2 tiles in flight (8 loads/wave)
  issue(0, 0); issue(1, 1);
  int kt = 0;
  for (; kt < nkt - 1; ++kt) {
    // tile kt's 4 loads (oldest) done; tile kt+1's 4 stay in flight
    asm volatile("s_waitcnt vmcnt(4)" ::: "memory");
    __builtin_amdgcn_s_barrier();
    compute(kt, kt & 1, kt + 2 < nkt);
  }
  asm volatile("s_waitcnt vmcnt(0)" ::: "memory");
  __builtin_amdgcn_s_barrier();
  compute(kt, kt & 1, false);

  if (EP == EP_RELU_MAX) {
#pragma unroll
    for (int ni = 0; ni < 2; ++ni) {
      const int n = n0 + wc * 32 + ni * 16 + l15;
      const float b = g.bias[n];
      float m = 0.f;
#pragma unroll
      for (int mi = 0; mi < 4; ++mi)
#pragma unroll
        for (int r = 0; r < 4; ++r)
          m = fmaxf(m, acc[mi][ni][r] + b);
      m = fmaxf(m, 0.f);
      m = fmaxf(m, __shfl_xor(m, 16));
      m = fmaxf(m, __shfl_xor(m, 32));
      if (l4 == 0) g.outf[(size_t)((m0 >> 6) + wr) * HD + n] = m;
    }
  } else {
#pragma unroll
    for (int mi = 0; mi < 4; ++mi)
#pragma unroll
      for (int r = 0; r < 4; ++r) {
        const int row = m0 + wr * 64 + mi * 16 + l4 * 4 + r;
#pragma unroll
        for (int ni = 0; ni < 2; ++ni) {
          const int n = n0 + wc * 32 + ni * 16 + l15;
          const size_t oi = (size_t)row * HD + n;
          float v = acc[mi][ni][r];
          if (EP == EP_TANH) {
            g.outb[oi] = f2bf(tanhf(v + g.bias[n] + 3.f * g.bias2[n]));
          } else if (EP == EP_MERGE) {
            float gg = v + g.aux2[(size_t)(row >> 6) * HD + n];
            float sg = 1.f / (1.f + expf(-gg));
            float o1v = bf2f(g.aux0[oi]);
            float ock = bf2f(g.aux1[oi]);
            g.outb[oi] = f2bf(fmaf(sg, o1v - ock, ock));
          } else {  // EP_RELU
            g.outb[oi] = f2bf(fmaxf(v + g.bias[n], 0.f));
          }
        }
      }
  }
}

extern "C" void kernel_launch(void* const* d_in, const int* in_sizes, int n_in,
                              void* d_out, int out_size, void* d_ws, size_t ws_size,
                              hipStream_t stream) {
  const float* enc_o = (const float*)d_in[0];
  const float* enc_q = (const float*)d_in[1];
  const int* om = (const int*)d_in[2];
  const int* qm = (const int*)d_in[3];
  const float* att_W1_w = (const float*)d_in[4];
  const float* att_W1_b = (const float*)d_in[5];
  const float* att_W2_w = (const float*)d_in[6];
  const float* att_W2_b = (const float*)d_in[7];
  const float* att_W3 = (const float*)d_in[8];
  const float* Wc_self_w = (const float*)d_in[9];
  const float* Wc_self_b = (const float*)d_in[10];
  const float* Wc_w = (const float*)d_in[11];
  const float* Wc_b = (const float*)d_in[12];
  const float* Va_w = (const float*)d_in[13];
  const float* Va_b = (const float*)d_in[14];
  const float* Wg_w = (const float*)d_in[15];
  const float* Wg_b = (const float*)d_in[16];
  const float* co_W1_w = (const float*)d_in[17];
  const float* co_W1_b = (const float*)d_in[18];
  const float* co_W2_w = (const float*)d_in[19];
  const float* co_W2_b = (const float*)d_in[20];
  const float* co_W3 = (const float*)d_in[21];
  const float* Wp_w = (const float*)d_in[22];
  const float* Wp_b = (const float*)d_in[23];
  const float* sa_W1_w = (const float*)d_in[24];
  const float* sa_W1_b = (const float*)d_in[25];
  const float* sa_W2_w = (const float*)d_in[26];
  const float* sa_W2_b = (const float*)d_in[27];
  const float* sa_W3 = (const float*)d_in[28];
  const float* Wf_w = (const float*)d_in[29];
  const float* Wf_b = (const float*)d_in[30];
  float* out = (float*)d_out;

  const int NTOK_O = 16384;
  const int HH = 768 * 768;

  float* ws = (float*)d_ws;
  size_t off = 0;
  auto carve = [&](size_t n) { float* p = ws + off; off += n; return p; };
  float* s1o   = carve(16384);
  float* s2o   = carve(16384);
  float* qco1  = carve(32768);
  float* sa1   = carve(16384);
  float* sa2   = carve(16384);
  float* Qpool = carve(196608);
  float* Qg    = carve(196608);
  float* A2buf = carve(2097152);   // PtG only
  float* r1 = carve(12582912);   // [-- | X1] -> [OPKb | X3]
  float* r2 = carve(12582912);   // [OCKb | X2] -> [PLOb | ..] -> opkw3
  float* r3 = carve(12582912);   // [MRGb | ..] -> [OSKb | X4]
  float* r4 = carve(12582912);   // [eobf | eow3] -> [PHIb | wall]
  if (ws_size < off * sizeof(float)) return;
  unsigned short* OPKb  = (unsigned short*)r1;
  unsigned short* X1    = (unsigned short*)(r1 + 6291456);
  unsigned short* X3    = (unsigned short*)(r1 + 6291456);
  unsigned short* OCKb  = (unsigned short*)r2;
  unsigned short* PLOb  = (unsigned short*)r2;
  unsigned short* opkw3 = (unsigned short*)r2;
  unsigned short* X2    = (unsigned short*)(r2 + 6291456);
  unsigned short* MRGb  = (unsigned short*)r3;
  unsigned short* OSKb  = (unsigned short*)r3;
  unsigned short* X4    = (unsigned short*)(r3 + 6291456);
  unsigned short* eobf  = (unsigned short*)r4;
  unsigned short* eow3  = (unsigned short*)(r4 + 6291456);   // dead after p1<3>
  unsigned short* PHIb  = (unsigned short*)r4;
  unsigned short* wall  = (unsigned short*)(r4 + 6291456);   // 768*9216 bf16 = 14.2 MB
  unsigned short* PtG   = (unsigned short*)A2buf;

  const dim3 GBIG(128, 6);  // m-fast

  // 1. fused enc_o prep + fused qpool (Va/coW1 dots inside)
  bfprep_dot_kernel<<<NTOK_O / 4, 256, 0, stream>>>(enc_o, att_W3, att_W1_w, att_W1_b,
                                                    att_W2_w, att_W2_b, eobf, eow3,
                                                    s1o, s2o, NTOK_O);
  qpool2_kernel<<<256, 256, 0, stream>>>(enc_q, Va_w, Va_b, co_W1_w, co_W1_b,
                                         qm, qco1, Qpool);

  // 2. p1<3> (uses eow3), then wconv_all (overwrites eow3 region), then p2<3>
  p1_kernel<3><<<768, 256, 0, stream>>>(eobf, eow3, s1o, s2o, om, PtG);
  {
    WcAllArgs wa{};
    wa.src[0] = Wc_self_w; wa.src[1] = Wc_w;        wa.src[2] = Wc_w + HH;
    wa.src[3] = Wg_w;      wa.src[4] = Wg_w + HH;
    wa.src[5] = Wp_w;      wa.src[6] = Wp_w + HH;   wa.src[7] = Wp_w + 2 * HH;
    wa.src[8] = Wf_w;      wa.src[9] = Wf_w + HH;   wa.src[10] = Wf_w + 2 * HH;
    wa.src[11] = Wf_w + 3 * HH;
    int bases[12] = {0, 768, 1536, 2304, 3072, 3840, 4608, 5376, 6144, 6912, 7680, 8448};
    for (int i = 0; i < 12; ++i) wa.basecol[i] = bases[i];
    wa.dst = wall;
    wconv_all_kernel<<<dim3(144, 12), 256, 0, stream>>>(wa);
  }
  p2_kernel<3><<<dim3(4, 256), 256, 0, stream>>>(eobf, PtG, eobf, nullptr, X1, X2);

  // 3. OCK = tanh([o1 | 3o1-CS | o1*CS] @ Wc + (Wc_self_b + 3*Wc_b))
  {
    MMArgs g{};
    g.a[0] = eobf; g.a[1] = X1; g.a[2] = X2;
    g.K = 2304; g.wt = wall + 0;
    g.bias = Wc_self_b; g.bias2 = Wc_b; g.outb = OCKb;
    mfma_gemm_kernel<EP_TANH><<<GBIG, 512, 0, stream>>>(g);
  }

  // 4. Qg (f32)
  {
    GemmArgs g{};
    g.a[0] = Qpool; g.w[0] = Wg_w + 2 * HH;
    g.nchunks = 1; g.bias = Wg_b; g.out = Qg;
    gemm_store_kernel<<<dim3(12, 4), 256, 0, stream>>>(g);
  }

  // 5. merged = G*o1 + (1-G)*OCK
  {
    MMArgs g{};
    g.a[0] = eobf; g.a[1] = OCKb;
    g.K = 1536; g.wt = wall + 2304; g.bias = nullptr;
    g.aux0 = eobf; g.aux1 = OCKb; g.aux2 = Qg; g.outb = MRGb;
    mfma_gemm_kernel<EP_MERGE><<<GBIG, 512, 0, stream>>>(g);
  }

  // 6. co-attention: poaa2 (A2 + ms2 fused)
  poaa2_kernel<<<dim3(2, 256), 256, 0, stream>>>(enc_q, MRGb, qco1, co_W2_w, co_W2_b,
                                                 qm, om, co_W3, PLOb, PHIb);

  // 7. OPK = relu([merged | PLO | PHI] @ Wp + b)
  {
    MMArgs g{};
    g.a[0] = MRGb; g.a[1] = PLOb; g.a[2] = PHIb;
    g.K = 2304; g.wt = wall + 3840; g.bias = Wp_b; g.outb = OPKb;
    mfma_gemm_kernel<EP_RELU><<<GBIG, 512, 0, stream>>>(g);
  }

  // 8. self-attention
  opkprep_kernel<<<NTOK_O / 4, 256, 0, stream>>>(OPKb, sa_W3, sa_W1_w, sa_W1_b,
                                                 sa_W2_w, sa_W2_b, opkw3, sa1, sa2, NTOK_O);
  p1_kernel<1><<<256, 256, 0, stream>>>(OPKb, opkw3, sa1, sa2, om, PtG);
  p2_kernel<1><<<dim3(4, 256), 256, 0, stream>>>(OPKb, PtG, OPKb, OSKb, X3, X4);

  // 9. out = max_lo relu([OPK | OSK | OPK-OSK | OPK*OSK] @ Wf + b)
  {
    MMArgs g{};
    g.a[0] = OPKb; g.a[1] = OSKb; g.a[2] = X3; g.a[3] = X4;
    g.K = 3072; g.wt = wall + 6144; g.bias = Wf_b; g.outf = out;
    mfma_gemm_kernel<EP_RELU_MAX><<<GBIG, 512, 0, stream>>>(g);
  }
}

// Round 18
// 599.302 us; speedup vs baseline: 1.0455x; 1.0455x over previous
//
#include <hip/hip_runtime.h>
#include <math.h>

// OptionCompareCell: B=64,C=4,LO=64,LQ=128,H=768
// Round 18: REVERT to round 16 exactly (best = 599us). Round 17's BK=64
//           regressed (LDS 64KB -> 2 blocks/CU -> FETCH 67.6->116.8MB,
//           111us GEMM). GEMM = 8-wave (512 thr), 128x128 tile, BK=32,
//           3-buffer two-barrier counted-vmcnt pipeline, XOR swizzle
//           (0 conflicts), m-fast grid, setprio around MFMA cluster.

#define NEGC (-10000.0f)
constexpr int HD = 768;
constexpr int KSTR = 9216;   // combined weight K-stride

constexpr int EP_TANH = 1;
constexpr int EP_MERGE = 2;
constexpr int EP_RELU = 3;
constexpr int EP_RELU_MAX = 4;

typedef __attribute__((ext_vector_type(8))) short bf16x8;
typedef __attribute__((ext_vector_type(8))) unsigned short u16x8;
typedef __attribute__((ext_vector_type(4))) unsigned short u16x4;
typedef __attribute__((ext_vector_type(4))) float f32x4;

__device__ inline void st8(float* dst, float4 a0, float4 a1) {
  dst[0] = a0.x; dst[1] = a0.y; dst[2] = a0.z; dst[3] = a0.w;
  dst[4] = a1.x; dst[5] = a1.y; dst[6] = a1.z; dst[7] = a1.w;
}

__device__ inline unsigned short f2bf(float x) {
  unsigned int u = __float_as_uint(x);
  u += 0x7fffu + ((u >> 16) & 1u);
  return (unsigned short)(u >> 16);
}

__device__ inline float bf2f(unsigned short u) {
  return __uint_as_float(((unsigned int)u) << 16);
}

__device__ inline u16x8 pack8(float4 a, float4 b) {
  u16x8 r;
  r[0] = f2bf(a.x); r[1] = f2bf(a.y); r[2] = f2bf(a.z); r[3] = f2bf(a.w);
  r[4] = f2bf(b.x); r[5] = f2bf(b.y); r[6] = f2bf(b.z); r[7] = f2bf(b.w);
  return r;
}

__device__ inline u16x4 pack4(float4 a) {
  u16x4 r;
  r[0] = f2bf(a.x); r[1] = f2bf(a.y); r[2] = f2bf(a.z); r[3] = f2bf(a.w);
  return r;
}

__device__ inline void gload_lds16(const unsigned short* src, unsigned short* dst) {
  __builtin_amdgcn_global_load_lds(
      (const __attribute__((address_space(1))) void*)src,
      (__attribute__((address_space(3))) void*)dst, 16, 0, 0);
}

// ---------------- fused enc_o prep: eobf, eow3, s1o, s2o in one pass ----------------
__global__ __launch_bounds__(256)
void bfprep_dot_kernel(const float* __restrict__ x, const float* __restrict__ w3,
                       const float* __restrict__ w1, const float* __restrict__ b1,
                       const float* __restrict__ w2, const float* __restrict__ b2,
                       unsigned short* __restrict__ xbf, unsigned short* __restrict__ xw3,
                       float* __restrict__ o1, float* __restrict__ o2, int ntok) {
  int tok = blockIdx.x * 4 + (threadIdx.x >> 6);
  int lane = threadIdx.x & 63;
  if (tok >= ntok) return;
  const float* xp = x + (size_t)tok * HD;
  unsigned short* xb = xbf + (size_t)tok * HD;
  unsigned short* xw = xw3 + (size_t)tok * HD;
  float s1 = 0.f, s2 = 0.f;
#pragma unroll
  for (int i = 0; i < 3; ++i) {
    int c = (lane + (i << 6)) << 2;
    float4 xv = *(const float4*)(xp + c);
    float4 w3v = *(const float4*)(w3 + c);
    float4 wa = *(const float4*)(w1 + c);
    float4 wb = *(const float4*)(w2 + c);
    s1 = fmaf(xv.x, wa.x, s1); s1 = fmaf(xv.y, wa.y, s1);
    s1 = fmaf(xv.z, wa.z, s1); s1 = fmaf(xv.w, wa.w, s1);
    s2 = fmaf(xv.x, wb.x, s2); s2 = fmaf(xv.y, wb.y, s2);
    s2 = fmaf(xv.z, wb.z, s2); s2 = fmaf(xv.w, wb.w, s2);
    *(u16x4*)(xb + c) = pack4(xv);
    float4 sv;
    sv.x = xv.x * w3v.x; sv.y = xv.y * w3v.y; sv.z = xv.z * w3v.z; sv.w = xv.w * w3v.w;
    *(u16x4*)(xw + c) = pack4(sv);
  }
#pragma unroll
  for (int off = 32; off; off >>= 1) {
    s1 += __shfl_xor(s1, off);
    s2 += __shfl_xor(s2, off);
  }
  if (lane == 0) { o1[tok] = s1 + b1[0]; o2[tok] = s2 + b2[0]; }
}

// ---------------- fused OPK prep: opkw3, sa1, sa2 in one pass ----------------
__global__ __launch_bounds__(256)
void opkprep_kernel(const unsigned short* __restrict__ x, const float* __restrict__ w3,
                    const float* __restrict__ w1, const float* __restrict__ b1,
                    const float* __restrict__ w2, const float* __restrict__ b2,
                    unsigned short* __restrict__ xw3,
                    float* __restrict__ o1, float* __restrict__ o2, int ntok) {
  int tok = blockIdx.x * 4 + (threadIdx.x >> 6);
  int lane = threadIdx.x & 63;
  if (tok >= ntok) return;
  const unsigned short* xp = x + (size_t)tok * HD;
  unsigned short* xw = xw3 + (size_t)tok * HD;
  float s1 = 0.f, s2 = 0.f;
#pragma unroll
  for (int i = 0; i < 3; ++i) {
    int c = (lane + (i << 6)) << 2;
    u16x4 xv = *(const u16x4*)(xp + c);
    float x0 = bf2f(xv[0]), x1 = bf2f(xv[1]), x2 = bf2f(xv[2]), x3 = bf2f(xv[3]);
    float4 w3v = *(const float4*)(w3 + c);
    float4 wa = *(const float4*)(w1 + c);
    float4 wb = *(const float4*)(w2 + c);
    s1 = fmaf(x0, wa.x, s1); s1 = fmaf(x1, wa.y, s1);
    s1 = fmaf(x2, wa.z, s1); s1 = fmaf(x3, wa.w, s1);
    s2 = fmaf(x0, wb.x, s2); s2 = fmaf(x1, wb.y, s2);
    s2 = fmaf(x2, wb.z, s2); s2 = fmaf(x3, wb.w, s2);
    u16x4 sv;
    sv[0] = f2bf(x0 * w3v.x); sv[1] = f2bf(x1 * w3v.y);
    sv[2] = f2bf(x2 * w3v.z); sv[3] = f2bf(x3 * w3v.w);
    *(u16x4*)(xw + c) = sv;
  }
#pragma unroll
  for (int off = 32; off; off >>= 1) {
    s1 += __shfl_xor(s1, off);
    s2 += __shfl_xor(s2, off);
  }
  if (lane == 0) { o1[tok] = s1 + b1[0]; o2[tok] = s2 + b2[0]; }
}

// ---- qpool2: per bc, fused Va/co_W1 dots + masked softmax + pooled Q ----
__global__ __launch_bounds__(256)
void qpool2_kernel(const float* __restrict__ q,
                   const float* __restrict__ Va_w, const float* __restrict__ Va_b,
                   const float* __restrict__ coW1_w, const float* __restrict__ coW1_b,
                   const int* __restrict__ qm,
                   float* __restrict__ qco1, float* __restrict__ Q) {
  __shared__ float qa_s[128];
  __shared__ float wgt[128];
  __shared__ float wred[4];
  const int t = threadIdx.x, bc = blockIdx.x;
  const int lane = t & 63, wv = t >> 6;
  const float* qb = q + (size_t)bc * (128 * HD);
  for (int it = 0; it < 32; ++it) {
    const int tl = it * 4 + wv;
    const float* xp = qb + (size_t)tl * HD;
    float s1 = 0.f, s2 = 0.f;
#pragma unroll
    for (int i = 0; i < 3; ++i) {
      int c = (lane + (i << 6)) << 2;
      float4 xv = *(const float4*)(xp + c);
      float4 wa = *(const float4*)(Va_w + c);
      float4 wb = *(const float4*)(coW1_w + c);
      s1 = fmaf(xv.x, wa.x, s1); s1 = fmaf(xv.y, wa.y, s1);
      s1 = fmaf(xv.z, wa.z, s1); s1 = fmaf(xv.w, wa.w, s1);
      s2 = fmaf(xv.x, wb.x, s2); s2 = fmaf(xv.y, wb.y, s2);
      s2 = fmaf(xv.z, wb.z, s2); s2 = fmaf(xv.w, wb.w, s2);
    }
#pragma unroll
    for (int off = 32; off; off >>= 1) {
      s1 += __shfl_xor(s1, off);
      s2 += __shfl_xor(s2, off);
    }
    if (lane == 0) {
      qa_s[tl] = s1 + Va_b[0];
      qco1[bc * 128 + tl] = s2 + coW1_b[0];
    }
  }
  __syncthreads();
  const int* qmp = qm + bc * 128;
  float v = -1e30f;
  if (t < 128) v = qa_s[t] + (1.f - (float)qmp[t]) * NEGC;
  float m = v;
#pragma unroll
  for (int off = 32; off; off >>= 1) m = fmaxf(m, __shfl_xor(m, off));
  if ((t & 63) == 0) wred[t >> 6] = m;
  __syncthreads();
  float gm = fmaxf(fmaxf(wred[0], wred[1]), fmaxf(wred[2], wred[3]));
  float e = (t < 128) ? expf(v - gm) : 0.f;
  float s = e;
#pragma unroll
  for (int off = 32; off; off >>= 1) s += __shfl_xor(s, off);
  __syncthreads();
  if ((t & 63) == 0) wred[t >> 6] = s;
  __syncthreads();
  float tot = wred[0] + wred[1] + wred[2] + wred[3];
  if (t < 128) wgt[t] = e / tot;
  __syncthreads();
  float* Qp = Q + (size_t)bc * HD;
  for (int d = t; d < HD; d += 256) {
    float acc = 0.f;
    for (int l = 0; l < 128; ++l) acc = fmaf(wgt[l], qb[(size_t)l * HD + d], acc);
    Qp[d] = acc;
  }
}

// ---------------- P1: S = U . Vw3^T (MFMA), softmax over u, write Pt[v][u] bf16 ----------------
template<int NJ>
__global__ __launch_bounds__(256)
void p1_kernel(const unsigned short* __restrict__ Xbf, const unsigned short* __restrict__ Xw3,
               const float* __restrict__ s1g, const float* __restrict__ s2g,
               const int* __restrict__ maskg, unsigned short* __restrict__ PtG) {
  __shared__ __align__(16) unsigned short Ua[64 * 136];
  __shared__ __align__(16) unsigned short Vb[64 * 136];
  __shared__ float Sbuf[64][66];
  __shared__ float red[4][64];
  const int t = threadIdx.x;
  int ubc, vbc;
  if (NJ == 1) {
    ubc = vbc = blockIdx.x;
  } else {
    const int b = blockIdx.x / 12, pr = blockIdx.x % 12;
    const int i = pr / 3, jj = pr % 3;
    const int j = jj + (jj >= i ? 1 : 0);
    vbc = (b << 2) + i; ubc = (b << 2) + j;
  }
  const unsigned short* U = Xbf + (size_t)ubc * (64 * HD);
  const unsigned short* V = Xw3 + (size_t)vbc * (64 * HD);
  const int w = t >> 6, lane = t & 63, l15 = lane & 15, l4 = lane >> 4;
  const int srow = t >> 2, scol = (t & 3) << 5;
  f32x4 acc[4] = {};
  for (int k0 = 0; k0 < HD; k0 += 128) {
    const unsigned short* up = U + (size_t)srow * HD + k0 + scol;
    const unsigned short* vp = V + (size_t)srow * HD + k0 + scol;
    unsigned short* ua = &Ua[srow * 136 + scol];
    unsigned short* vb = &Vb[srow * 136 + scol];
#pragma unroll
    for (int z = 0; z < 4; ++z) {
      *(u16x8*)(ua + z * 8) = *(const u16x8*)(up + z * 8);
      *(u16x8*)(vb + z * 8) = *(const u16x8*)(vp + z * 8);
    }
    __syncthreads();
#pragma unroll
    for (int ks = 0; ks < 4; ++ks) {
      bf16x8 af = *(const bf16x8*)(&Ua[(w * 16 + l15) * 136 + ks * 32 + l4 * 8]);
#pragma unroll
      for (int n = 0; n < 4; ++n) {
        bf16x8 bf = *(const bf16x8*)(&Vb[(n * 16 + l15) * 136 + ks * 32 + l4 * 8]);
        acc[n] = __builtin_amdgcn_mfma_f32_16x16x32_bf16(af, bf, acc[n], 0, 0, 0);
      }
    }
    __syncthreads();
  }
  {
    float s1v[4];
#pragma unroll
    for (int r = 0; r < 4; ++r) {
      int u = w * 16 + l4 * 4 + r;
      s1v[r] = s1g[ubc * 64 + u] + (1.f - (float)maskg[ubc * 64 + u]) * NEGC;
    }
#pragma unroll
    for (int n = 0; n < 4; ++n) {
      int v = n * 16 + l15;
      float s2v = s2g[vbc * 64 + v] + (1.f - (float)maskg[vbc * 64 + v]) * NEGC;
#pragma unroll
      for (int r = 0; r < 4; ++r)
        Sbuf[w * 16 + l4 * 4 + r][v] = acc[n][r] + s1v[r] + s2v;
    }
  }
  __syncthreads();
  {
    const int v = t & 63, part = t >> 6;
    float m = -1e30f;
#pragma unroll
    for (int z = 0; z < 16; ++z) m = fmaxf(m, Sbuf[part * 16 + z][v]);
    red[part][v] = m;
    __syncthreads();
    float gm = fmaxf(fmaxf(red[0][v], red[1][v]), fmaxf(red[2][v], red[3][v]));
    float s = 0.f;
#pragma unroll
    for (int z = 0; z < 16; ++z) {
      float e = expf(Sbuf[part * 16 + z][v] - gm);
      Sbuf[part * 16 + z][v] = e;
      s += e;
    }
    __syncthreads();
    red[part][v] = s;
    __syncthreads();
    float cinv = 1.f / (red[0][v] + red[1][v] + red[2][v] + red[3][v]);
    unsigned short* pt = PtG + (size_t)blockIdx.x * 4096 + v * 64 + part * 16;
#pragma unroll
    for (int z = 0; z < 16; ++z) pt[z] = f2bf(Sbuf[part * 16 + z][v] * cinv);
  }
}

// ---- P2: ctx = sum_j Pt_j . U_j ; fused epilogue: NJ=3 -> X1,X2 ; NJ=1 -> OSK,X3,X4 ----
template<int NJ>
__global__ __launch_bounds__(256)
void p2_kernel(const unsigned short* __restrict__ Xbf, const unsigned short* __restrict__ PtG,
               const unsigned short* __restrict__ Oi,
               unsigned short* __restrict__ osk,
               unsigned short* __restrict__ y1, unsigned short* __restrict__ y2) {
  __shared__ __align__(16) unsigned short Pts[NJ][64 * 72];
  __shared__ __align__(16) unsigned short U2[64 * 192];
  const int t = threadIdx.x;
  const int dq = blockIdx.x, bc = blockIdx.y;
  const int d0 = dq * 192;
  const int b = bc >> 2, i = bc & 3;
  const int w = t >> 6, lane = t & 63, l15 = lane & 15, l4 = lane >> 4;
  {
    const int v = t >> 2, cs = (t & 3) << 4;
#pragma unroll
    for (int jj = 0; jj < NJ; ++jj) {
      size_t src = (NJ == 1 ? (size_t)bc : (size_t)(b * 12 + i * 3 + jj)) * 4096 + v * 64 + cs;
      *(u16x8*)(&Pts[jj][v * 72 + cs]) = *(const u16x8*)(PtG + src);
      *(u16x8*)(&Pts[jj][v * 72 + cs + 8]) = *(const u16x8*)(PtG + src + 8);
    }
  }
  f32x4 acc[4][3] = {};
  const int su = t >> 2, sc0 = (t & 3) * 48;
  const int sswz = ((su >> 3) & 3) << 5;
  for (int jj = 0; jj < NJ; ++jj) {
    const int ubc = (NJ == 1) ? bc : ((b << 2) + (jj + (jj >= i ? 1 : 0)));
    __syncthreads();
    {
      const unsigned short* up = Xbf + (size_t)ubc * (64 * HD) + (size_t)su * HD + d0 + sc0;
#pragma unroll
      for (int it = 0; it < 6; ++it) {
        u16x8 vdat = *(const u16x8*)(up + it * 8);
        *(u16x8*)((char*)U2 + ((su * 384 + (sc0 + it * 8) * 2) ^ sswz)) = vdat;
      }
    }
    __syncthreads();
    const unsigned short* ptj = &Pts[jj][0];
#pragma unroll
    for (int ks = 0; ks < 2; ++ks) {
      bf16x8 bfr[3];
#pragma unroll
      for (int n = 0; n < 3; ++n) {
        const int col = (w * 3 + n) * 16 + l15;
#pragma unroll
        for (int e = 0; e < 8; ++e) {
          const int uk = ks * 32 + l4 * 8 + e;
          const int byte = (uk * 384 + col * 2) ^ (((uk >> 3) & 3) << 5);
          bfr[n][e] = *(const short*)((const char*)U2 + byte);
        }
      }
#pragma unroll
      for (int m = 0; m < 4; ++m) {
        bf16x8 af = *(const bf16x8*)(ptj + (m * 16 + l15) * 72 + ks * 32 + l4 * 8);
#pragma unroll
        for (int n = 0; n < 3; ++n)
          acc[m][n] = __builtin_amdgcn_mfma_f32_16x16x32_bf16(af, bfr[n], acc[m][n], 0, 0, 0);
      }
    }
  }
  const unsigned short* oip = Oi + (size_t)bc * (64 * HD);
  const size_t obase = (size_t)bc * (64 * HD);
#pragma unroll
  for (int m = 0; m < 4; ++m)
#pragma unroll
    for (int n = 0; n < 3; ++n) {
      const int d = d0 + (w * 3 + n) * 16 + l15;
#pragma unroll
      for (int r = 0; r < 4; ++r) {
        const int v = m * 16 + l4 * 4 + r;
        const size_t idx = obase + (size_t)v * HD + d;
        const float cs = acc[m][n][r];
        const float oi = bf2f(oip[(size_t)v * HD + d]);
        if (NJ == 3) {
          y1[idx] = f2bf(fmaf(3.f, oi, -cs));
          y2[idx] = f2bf(oi * cs);
        } else {
          osk[idx] = f2bf(cs);
          y1[idx] = f2bf(oi - cs);
          y2[idx] = f2bf(oi * cs);
        }
      }
    }
}

// ---- POAA fused with A2 + ms2 (computed during Bm staging) ----
__global__ __launch_bounds__(256)
void poaa2_kernel(const float* __restrict__ qin, const unsigned short* __restrict__ mergedb,
                  const float* __restrict__ qco1,
                  const float* __restrict__ coW2_w, const float* __restrict__ coW2_b,
                  const int* __restrict__ qm, const int* __restrict__ om,
                  const float* __restrict__ w3,
                  unsigned short* __restrict__ PLO, unsigned short* __restrict__ PHI) {
  __shared__ __align__(16) char smem[77312];
  __shared__ float red[4][64];
  __shared__ float rowm[128], rowfac[128];
  __shared__ float colfac[64];
  __shared__ float ms2_s[64];
  __shared__ float gmax_s;
  float* T = (float*)smem;                                   // [128][65] f32
  unsigned short* Aq = (unsigned short*)smem;                 // [128][72] (phase0)
  unsigned short* Bm = (unsigned short*)(smem + 18432);       // [64][72]  (phase0)
  unsigned short* Tt = (unsigned short*)(smem + 33280);       // [64][136]
  unsigned short* Tft = (unsigned short*)(smem + 50688);      // [64][136]
  unsigned short* M2bf = (unsigned short*)(smem + 68096);     // [64][72]
  unsigned short* Qc = (unsigned short*)smem;                 // [128][72] (chunk phase)
  unsigned short* Mc = (unsigned short*)(smem + 18432);       // [64][72]

  const int t = threadIdx.x, dqh = blockIdx.x, bc = blockIdx.y;
  const int w = t >> 6, lane = t & 63, l15 = lane & 15, l4 = lane >> 4;
  const float* qp = qin + (size_t)bc * (128 * HD);
  const unsigned short* mp = mergedb + (size_t)bc * (64 * HD);
  const float* qc = qco1 + bc * 128;
  const int* qmp = qm + bc * 128;
  const int* omp = om + bc * 64;

  // ---- phase 0: A2 = (q*w3).merged^T via MFMA ; ms2 dot rides the Bm staging ----
  {
    const int arow = t >> 1, acs = (t & 1) << 5;
    const int brow = t >> 2, bcs = (t & 3) << 4;
    f32x4 acc[2][4] = {};
    float msacc = 0.f;
    for (int k0 = 0; k0 < HD; k0 += 64) {
      {
        const float* p = qp + (size_t)arow * HD + k0 + acs;
        const float* wp = w3 + k0 + acs;
        unsigned short* dst = &Aq[arow * 72 + acs];
#pragma unroll
        for (int z = 0; z < 4; ++z) {
          float4 a = *(const float4*)(p + z * 8);
          float4 b = *(const float4*)(p + z * 8 + 4);
          float4 wa = *(const float4*)(wp + z * 8);
          float4 wb = *(const float4*)(wp + z * 8 + 4);
          a.x *= wa.x; a.y *= wa.y; a.z *= wa.z; a.w *= wa.w;
          b.x *= wb.x; b.y *= wb.y; b.z *= wb.z; b.w *= wb.w;
          *(u16x8*)(dst + z * 8) = pack8(a, b);
        }
      }
      {
        const unsigned short* p = mp + (size_t)brow * HD + k0 + bcs;
        unsigned short* dst = &Bm[brow * 72 + bcs];
        u16x8 v0 = *(const u16x8*)(p);
        u16x8 v1 = *(const u16x8*)(p + 8);
        *(u16x8*)(dst) = v0;
        *(u16x8*)(dst + 8) = v1;
        const float* wp = coW2_w + k0 + bcs;
        float4 wa = *(const float4*)(wp);
        float4 wb = *(const float4*)(wp + 4);
        float4 wc = *(const float4*)(wp + 8);
        float4 wd = *(const float4*)(wp + 12);
        msacc = fmaf(bf2f(v0[0]), wa.x, msacc); msacc = fmaf(bf2f(v0[1]), wa.y, msacc);
        msacc = fmaf(bf2f(v0[2]), wa.z, msacc); msacc = fmaf(bf2f(v0[3]), wa.w, msacc);
        msacc = fmaf(bf2f(v0[4]), wb.x, msacc); msacc = fmaf(bf2f(v0[5]), wb.y, msacc);
        msacc = fmaf(bf2f(v0[6]), wb.z, msacc); msacc = fmaf(bf2f(v0[7]), wb.w, msacc);
        msacc = fmaf(bf2f(v1[0]), wc.x, msacc); msacc = fmaf(bf2f(v1[1]), wc.y, msacc);
        msacc = fmaf(bf2f(v1[2]), wc.z, msacc); msacc = fmaf(bf2f(v1[3]), wc.w, msacc);
        msacc = fmaf(bf2f(v1[4]), wd.x, msacc); msacc = fmaf(bf2f(v1[5]), wd.y, msacc);
        msacc = fmaf(bf2f(v1[6]), wd.z, msacc); msacc = fmaf(bf2f(v1[7]), wd.w, msacc);
      }
      __syncthreads();
#pragma unroll
      for (int ks = 0; ks < 2; ++ks) {
        bf16x8 af[2], bf[4];
#pragma unroll
        for (int m = 0; m < 2; ++m)
          af[m] = *(const bf16x8*)(&Aq[(w * 32 + m * 16 + l15) * 72 + ks * 32 + l4 * 8]);
#pragma unroll
        for (int n = 0; n < 4; ++n)
          bf[n] = *(const bf16x8*)(&Bm[(n * 16 + l15) * 72 + ks * 32 + l4 * 8]);
#pragma unroll
        for (int m = 0; m < 2; ++m)
#pragma unroll
          for (int n = 0; n < 4; ++n)
            acc[m][n] = __builtin_amdgcn_mfma_f32_16x16x32_bf16(af[m], bf[n], acc[m][n], 0, 0, 0);
      }
      __syncthreads();
    }
    msacc += __shfl_xor(msacc, 1);
    msacc += __shfl_xor(msacc, 2);
    if ((t & 3) == 0) ms2_s[brow] = msacc + coW2_b[0];
    __syncthreads();
#pragma unroll
    for (int n = 0; n < 4; ++n) {
      const int v = n * 16 + l15;
      const float ct = ms2_s[v] + (1.f - (float)omp[v]) * NEGC;
#pragma unroll
      for (int m = 0; m < 2; ++m)
#pragma unroll
        for (int r = 0; r < 4; ++r) {
          const int qrow = w * 32 + m * 16 + l4 * 4 + r;
          const float rt = qc[qrow] + (1.f - (float)qmp[qrow]) * NEGC;
          T[qrow * 65 + v] = acc[m][n][r] + rt + ct;
        }
    }
  }
  __syncthreads();
  // ---- stats ----
  {
    int qrow = t >> 1, h = t & 1;
    float m = -1e30f;
    for (int v = h * 32; v < h * 32 + 32; ++v) m = fmaxf(m, T[qrow * 65 + v]);
    m = fmaxf(m, __shfl_xor(m, 1));
    float s = 0.f;
    for (int v = h * 32; v < h * 32 + 32; ++v) s += expf(T[qrow * 65 + v] - m);
    s += __shfl_xor(s, 1);
    if (h == 0) { rowm[qrow] = m; rowfac[qrow] = s; }
  }
  float colm_loc = 0.f;
  {
    int v = t & 63, part = t >> 6;
    float m = -1e30f;
    for (int qq = part * 32; qq < part * 32 + 32; ++qq) m = fmaxf(m, T[qq * 65 + v]);
    red[part][v] = m;
    __syncthreads();
    float cm = fmaxf(fmaxf(red[0][v], red[1][v]), fmaxf(red[2][v], red[3][v]));
    float s = 0.f;
    for (int qq = part * 32; qq < part * 32 + 32; ++qq) s += expf(T[qq * 65 + v] - cm);
    __syncthreads();
    red[part][v] = s;
    __syncthreads();
    if (part == 0) { colm_loc = cm; colfac[v] = red[0][v] + red[1][v] + red[2][v] + red[3][v]; }
  }
  __syncthreads();
  if (t < 64) {
    float m = fmaxf(rowm[t], rowm[t + 64]);
#pragma unroll
    for (int off = 32; off; off >>= 1) m = fmaxf(m, __shfl_xor(m, off));
    if (t == 0) gmax_s = m;
  }
  __syncthreads();
  const float gmax = gmax_s;
  if (t < 128) rowfac[t] = expf(fminf(gmax - rowm[t], 60.f)) / rowfac[t];
  if (t < 64) colfac[t] = expf(fminf(gmax - colm_loc, 60.f)) / colfac[t];
  __syncthreads();
  {
    const int o = t >> 2, qs = (t & 3) << 5;
    for (int z = 0; z < 32; ++z) {
      const int qq = qs + z;
      float e = expf(T[qq * 65 + o] - gmax);
      Tt[o * 136 + qq] = f2bf(e);
      Tft[o * 136 + qq] = f2bf(e * rowfac[qq]);
    }
  }
  __syncthreads();
  {
    f32x4 m2acc[4] = {};
#pragma unroll
    for (int ks = 0; ks < 4; ++ks) {
      bf16x8 af = *(const bf16x8*)(&Tt[(w * 16 + l15) * 136 + ks * 32 + l4 * 8]);
#pragma unroll
      for (int n = 0; n < 4; ++n) {
        bf16x8 bf = *(const bf16x8*)(&Tft[(n * 16 + l15) * 136 + ks * 32 + l4 * 8]);
        m2acc[n] = __builtin_amdgcn_mfma_f32_16x16x32_bf16(af, bf, m2acc[n], 0, 0, 0);
      }
    }
#pragma unroll
    for (int n = 0; n < 4; ++n)
#pragma unroll
      for (int r = 0; r < 4; ++r) {
        const int o = w * 16 + l4 * 4 + r;
        M2bf[o * 72 + n * 16 + l15] = f2bf(colfac[o] * m2acc[n][r]);
      }
  }
  // ---- chunk phase (d-half dqh) ----
  const int dql = t >> 1, dqs = (t & 1) << 5;
  const int dml = t >> 2, dms = (t & 3) << 4;
  const int swq = ((dql >> 3) & 3) << 5;
  const int swm = ((dml >> 3) & 3) << 5;
  unsigned short* plo = PLO + (size_t)bc * (64 * HD);
  unsigned short* phi = PHI + (size_t)bc * (64 * HD);
  for (int dc = dqh * 6; dc < dqh * 6 + 6; ++dc) {
    const int d0 = dc * 64;
    __syncthreads();
    {
      const float* p = qp + (size_t)dql * HD + d0 + dqs;
#pragma unroll
      for (int z = 0; z < 4; ++z) {
        float4 a = *(const float4*)(p + z * 8);
        float4 b = *(const float4*)(p + z * 8 + 4);
        *(u16x8*)((char*)Qc + ((dql * 144 + (dqs + z * 8) * 2) ^ swq)) = pack8(a, b);
      }
    }
    {
      const unsigned short* p = mp + (size_t)dml * HD + d0 + dms;
      *(u16x8*)((char*)Mc + ((dml * 144 + dms * 2) ^ swm)) = *(const u16x8*)p;
      *(u16x8*)((char*)Mc + ((dml * 144 + (dms + 8) * 2) ^ swm)) = *(const u16x8*)(p + 8);
    }
    __syncthreads();
    const int col = w * 16 + l15;
    f32x4 lacc[4] = {};
#pragma unroll
    for (int ks = 0; ks < 4; ++ks) {
      bf16x8 bf;
#pragma unroll
      for (int e = 0; e < 8; ++e) {
        const int qq = ks * 32 + l4 * 8 + e;
        bf[e] = *(const short*)((const char*)Qc + ((qq * 144 + col * 2) ^ (((qq >> 3) & 3) << 5)));
      }
#pragma unroll
      for (int m = 0; m < 4; ++m) {
        bf16x8 af = *(const bf16x8*)(&Tt[(m * 16 + l15) * 136 + ks * 32 + l4 * 8]);
        lacc[m] = __builtin_amdgcn_mfma_f32_16x16x32_bf16(af, bf, lacc[m], 0, 0, 0);
      }
    }
    f32x4 pacc[4] = {};
#pragma unroll
    for (int ks = 0; ks < 2; ++ks) {
      bf16x8 bf;
#pragma unroll
      for (int e = 0; e < 8; ++e) {
        const int vv = ks * 32 + l4 * 8 + e;
        bf[e] = *(const short*)((const char*)Mc + ((vv * 144 + col * 2) ^ (((vv >> 3) & 3) << 5)));
      }
#pragma unroll
      for (int m = 0; m < 4; ++m) {
        bf16x8 af = *(const bf16x8*)(&M2bf[(m * 16 + l15) * 72 + ks * 32 + l4 * 8]);
        pacc[m] = __builtin_amdgcn_mfma_f32_16x16x32_bf16(af, bf, pacc[m], 0, 0, 0);
      }
    }
#pragma unroll
    for (int m = 0; m < 4; ++m)
#pragma unroll
      for (int r = 0; r < 4; ++r) {
        const int o = m * 16 + l4 * 4 + r;
        const int d = d0 + w * 16 + l15;
        plo[(size_t)o * HD + d] = f2bf(colfac[o] * lacc[m][r]);
        phi[(size_t)o * HD + d] = f2bf(pacc[m][r]);
      }
  }
}

// ---------------- small f32 GEMM (Qg only) ----------------
struct GemmArgs {
  const float* a[4];
  const float* w[4];
  int nchunks;
  const float* bias;
  float* out;
};

__global__ __launch_bounds__(256)
void gemm_store_kernel(GemmArgs g) {
  __shared__ float As[64][33];
  __shared__ float Ws[32][65];
  const int t = threadIdx.x;
  const int m0 = blockIdx.y << 6, n0 = blockIdx.x << 6;
  const int tr = t >> 4, tc = t & 15;
  float acc[4][4];
#pragma unroll
  for (int x = 0; x < 4; ++x)
#pragma unroll
    for (int y = 0; y < 4; ++y) acc[x][y] = 0.f;
  const int arow = t >> 2, acs = (t & 3) << 3;
  const int wrow = t >> 3, wcs = (t & 7) << 3;
  for (int c = 0; c < g.nchunks; ++c) {
    const float* Ap = g.a[c] + (size_t)(m0 + arow) * HD + acs;
    const float* Wp = g.w[c] + (size_t)wrow * HD + n0 + wcs;
    for (int k0 = 0; k0 < HD; k0 += 32) {
      float4 a0 = *(const float4*)(Ap + k0);
      float4 a1 = *(const float4*)(Ap + k0 + 4);
      st8(&As[arow][acs], a0, a1);
      float4 w0 = *(const float4*)(Wp + (size_t)k0 * HD);
      float4 w1 = *(const float4*)(Wp + (size_t)k0 * HD + 4);
      st8(&Ws[wrow][wcs], w0, w1);
      __syncthreads();
#pragma unroll
      for (int kk = 0; kk < 32; ++kk) {
        float av[4], bv[4];
#pragma unroll
        for (int x = 0; x < 4; ++x) av[x] = As[(tr << 2) + x][kk];
#pragma unroll
        for (int y = 0; y < 4; ++y) bv[y] = Ws[kk][(tc << 2) + y];
#pragma unroll
        for (int x = 0; x < 4; ++x)
#pragma unroll
          for (int y = 0; y < 4; ++y) acc[x][y] = fmaf(av[x], bv[y], acc[x][y]);
      }
      __syncthreads();
    }
  }
#pragma unroll
  for (int x = 0; x < 4; ++x) {
    const int r = m0 + (tr << 2) + x;
#pragma unroll
    for (int y = 0; y < 4; ++y) {
      const int n = n0 + (tc << 2) + y;
      g.out[(size_t)r * HD + n] = acc[x][y] + g.bias[n];
    }
  }
}

// ---------------- wconv_all: 12 weight slices -> wall[768][9216] bf16 ----------------
struct WcAllArgs {
  const float* src[12];
  int basecol[12];
  unsigned short* dst;
};

__global__ __launch_bounds__(256)
void wconv_all_kernel(WcAllArgs g) {
  __shared__ float tile[64][65];
  const int slice = blockIdx.y;
  const float* src = g.src[slice];
  const int bi = blockIdx.x % 12, bj = blockIdx.x / 12;
  const int t = threadIdx.x;
  const int r = t >> 2, cseg = (t & 3) << 4;
  const float* p = src + (size_t)(bi * 64 + r) * HD + bj * 64 + cseg;
#pragma unroll
  for (int j = 0; j < 16; j += 4) {
    float4 v = *(const float4*)(p + j);
    tile[r][cseg + j + 0] = v.x; tile[r][cseg + j + 1] = v.y;
    tile[r][cseg + j + 2] = v.z; tile[r][cseg + j + 3] = v.w;
  }
  __syncthreads();
  unsigned short* q = g.dst + (size_t)(bj * 64 + r) * KSTR + g.basecol[slice] + bi * 64 + cseg;
  u16x8 lo, hi;
#pragma unroll
  for (int j = 0; j < 8; ++j) lo[j] = f2bf(tile[cseg + j][r]);
#pragma unroll
  for (int j = 0; j < 8; ++j) hi[j] = f2bf(tile[cseg + 8 + j][r]);
  *(u16x8*)q = lo;
  *(u16x8*)(q + 8) = hi;
}

// ---- bf16 MFMA GEMM: 8-wave blocks, same 3-deep two-barrier pipeline ----
struct MMArgs {
  const unsigned short* a[4];   // per-768-chunk bf16 sources (all mode-0)
  int K;
  const unsigned short* wt;     // wall + basecol, row stride KSTR
  const float* bias;
  const float* bias2;           // EP_TANH: bias + 3*bias2
  const unsigned short* aux0;   // o1 bf16  (EP_MERGE)
  const unsigned short* aux1;   // OCK bf16 (EP_MERGE)
  const float* aux2;            // Qg f32   (EP_MERGE)
  float* outf;                  // EP_RELU_MAX
  unsigned short* outb;         // others
};

template<int EP>
__global__ __launch_bounds__(512)
void mfma_gemm_kernel(MMArgs g) {
  __shared__ __align__(16) unsigned short As[3][128 * 32];
  __shared__ __align__(16) unsigned short Bs[3][128 * 32];
  const int t = threadIdx.x;
  const int lane = t & 63, w = t >> 6;       // 8 waves
  const int wr = w >> 2, wc = w & 3;          // 2 x 4 decomposition
  const int m0 = blockIdx.x << 7, n0 = blockIdx.y << 7;  // m-fast grid
  const int l15 = lane & 15, l4 = lane >> 4;
  f32x4 acc[4][2] = {};

  // staging: wave w covers rows w*16..w*16+15 (1 issue A + 1 issue B per tile).
  // XOR swizzle formulas identical to r12 (base-16-invariant).
  const int srow = w * 16 + (lane >> 2);
  const int gcol = (((lane & 3) ^ ((lane >> 3) & 3))) * 8;   // shorts
  const int rsw = (l15 >> 1) & 3;
  const int rcol = ((l4 ^ rsw)) * 8;                          // shorts

  const int nkt = g.K >> 5;

  auto issue = [&](int kt, int buf) {
    const int c = kt / 24;
    const int koff = (kt - c * 24) << 5;
    const unsigned short* ap = g.a[c] + (size_t)(m0 + srow) * HD + koff + gcol;
    const unsigned short* bp = g.wt + (size_t)(n0 + srow) * KSTR + (kt << 5) + gcol;
    gload_lds16(ap, &As[buf][w * 512]);
    gload_lds16(bp, &Bs[buf][w * 512]);
  };

  auto compute = [&](int kt, int buf, bool prefetch) {
    bf16x8 af[4], bfr[2];
#pragma unroll
    for (int mi = 0; mi < 4; ++mi)
      af[mi] = *(const bf16x8*)(&As[buf][(wr * 64 + mi * 16 + l15) * 32 + rcol]);
#pragma unroll
    for (int ni = 0; ni < 2; ++ni)
      bfr[ni] = *(const bf16x8*)(&Bs[buf][(wc * 32 + ni * 16 + l15) * 32 + rcol]);
    asm volatile("s_waitcnt lgkmcnt(0)" ::: "memory");  // my frags in regs
    __builtin_amdgcn_s_barrier();                        // everyone done reading buf
    if (prefetch) issue(kt + 3, buf);                    // safe to overwrite now
    __builtin_amdgcn_s_setprio(1);
#pragma unroll
    for (int mi = 0; mi < 4; ++mi)
#pragma unroll
      for (int ni = 0; ni < 2; ++ni)
        acc[mi][ni] = __builtin_amdgcn_mfma_f32_16x16x32_bf16(af[mi], bfr[ni], acc[mi][ni], 0, 0, 0);
    __builtin_amdgcn_s_setprio(0);
  };

  // prologue: 3 tiles in flight (6 loads/wave)
  issue(0, 0); issue(1, 1); issue(2, 2);
  int buf = 0;
  int kt = 0;
  for (; kt < nkt - 2; ++kt) {
    // tile kt's 2 loads (oldest) done; tiles kt+1,kt+2 (4 loads) stay in flight
    asm volatile("s_waitcnt vmcnt(4)" ::: "memory");
    __builtin_amdgcn_s_barrier();
    compute(kt, buf, kt + 3 < nkt);
    buf = (buf == 2) ? 0 : buf + 1;
  }
  asm volatile("s_waitcnt vmcnt(2)" ::: "memory");
  __builtin_amdgcn_s_barrier();
  compute(kt, buf, false);
  buf = (buf == 2) ? 0 : buf + 1;
  ++kt;
  asm volatile("s_waitcnt vmcnt(0)" ::: "memory");
  __builtin_amdgcn_s_barrier();
  compute(kt, buf, false);

  if (EP == EP_RELU_MAX) {
#pragma unroll
    for (int ni = 0; ni < 2; ++ni) {
      const int n = n0 + wc * 32 + ni * 16 + l15;
      const float b = g.bias[n];
      float m = 0.f;
#pragma unroll
      for (int mi = 0; mi < 4; ++mi)
#pragma unroll
        for (int r = 0; r < 4; ++r)
          m = fmaxf(m, acc[mi][ni][r] + b);
      m = fmaxf(m, 0.f);
      m = fmaxf(m, __shfl_xor(m, 16));
      m = fmaxf(m, __shfl_xor(m, 32));
      if (l4 == 0) g.outf[(size_t)((m0 >> 6) + wr) * HD + n] = m;
    }
  } else {
#pragma unroll
    for (int mi = 0; mi < 4; ++mi)
#pragma unroll
      for (int r = 0; r < 4; ++r) {
        const int row = m0 + wr * 64 + mi * 16 + l4 * 4 + r;
#pragma unroll
        for (int ni = 0; ni < 2; ++ni) {
          const int n = n0 + wc * 32 + ni * 16 + l15;
          const size_t oi = (size_t)row * HD + n;
          float v = acc[mi][ni][r];
          if (EP == EP_TANH) {
            g.outb[oi] = f2bf(tanhf(v + g.bias[n] + 3.f * g.bias2[n]));
          } else if (EP == EP_MERGE) {
            float gg = v + g.aux2[(size_t)(row >> 6) * HD + n];
            float sg = 1.f / (1.f + expf(-gg));
            float o1v = bf2f(g.aux0[oi]);
            float ock = bf2f(g.aux1[oi]);
            g.outb[oi] = f2bf(fmaf(sg, o1v - ock, ock));
          } else {  // EP_RELU
            g.outb[oi] = f2bf(fmaxf(v + g.bias[n], 0.f));
          }
        }
      }
  }
}

extern "C" void kernel_launch(void* const* d_in, const int* in_sizes, int n_in,
                              void* d_out, int out_size, void* d_ws, size_t ws_size,
                              hipStream_t stream) {
  const float* enc_o = (const float*)d_in[0];
  const float* enc_q = (const float*)d_in[1];
  const int* om = (const int*)d_in[2];
  const int* qm = (const int*)d_in[3];
  const float* att_W1_w = (const float*)d_in[4];
  const float* att_W1_b = (const float*)d_in[5];
  const float* att_W2_w = (const float*)d_in[6];
  const float* att_W2_b = (const float*)d_in[7];
  const float* att_W3 = (const float*)d_in[8];
  const float* Wc_self_w = (const float*)d_in[9];
  const float* Wc_self_b = (const float*)d_in[10];
  const float* Wc_w = (const float*)d_in[11];
  const float* Wc_b = (const float*)d_in[12];
  const float* Va_w = (const float*)d_in[13];
  const float* Va_b = (const float*)d_in[14];
  const float* Wg_w = (const float*)d_in[15];
  const float* Wg_b = (const float*)d_in[16];
  const float* co_W1_w = (const float*)d_in[17];
  const float* co_W1_b = (const float*)d_in[18];
  const float* co_W2_w = (const float*)d_in[19];
  const float* co_W2_b = (const float*)d_in[20];
  const float* co_W3 = (const float*)d_in[21];
  const float* Wp_w = (const float*)d_in[22];
  const float* Wp_b = (const float*)d_in[23];
  const float* sa_W1_w = (const float*)d_in[24];
  const float* sa_W1_b = (const float*)d_in[25];
  const float* sa_W2_w = (const float*)d_in[26];
  const float* sa_W2_b = (const float*)d_in[27];
  const float* sa_W3 = (const float*)d_in[28];
  const float* Wf_w = (const float*)d_in[29];
  const float* Wf_b = (const float*)d_in[30];
  float* out = (float*)d_out;

  const int NTOK_O = 16384;
  const int HH = 768 * 768;

  float* ws = (float*)d_ws;
  size_t off = 0;
  auto carve = [&](size_t n) { float* p = ws + off; off += n; return p; };
  float* s1o   = carve(16384);
  float* s2o   = carve(16384);
  float* qco1  = carve(32768);
  float* sa1   = carve(16384);
  float* sa2   = carve(16384);
  float* Qpool = carve(196608);
  float* Qg    = carve(196608);
  float* A2buf = carve(2097152);   // PtG only
  float* r1 = carve(12582912);   // [-- | X1] -> [OPKb | X3]
  float* r2 = carve(12582912);   // [OCKb | X2] -> [PLOb | ..] -> opkw3
  float* r3 = carve(12582912);   // [MRGb | ..] -> [OSKb | X4]
  float* r4 = carve(12582912);   // [eobf | eow3] -> [PHIb | wall]
  if (ws_size < off * sizeof(float)) return;
  unsigned short* OPKb  = (unsigned short*)r1;
  unsigned short* X1    = (unsigned short*)(r1 + 6291456);
  unsigned short* X3    = (unsigned short*)(r1 + 6291456);
  unsigned short* OCKb  = (unsigned short*)r2;
  unsigned short* PLOb  = (unsigned short*)r2;
  unsigned short* opkw3 = (unsigned short*)r2;
  unsigned short* X2    = (unsigned short*)(r2 + 6291456);
  unsigned short* MRGb  = (unsigned short*)r3;
  unsigned short* OSKb  = (unsigned short*)r3;
  unsigned short* X4    = (unsigned short*)(r3 + 6291456);
  unsigned short* eobf  = (unsigned short*)r4;
  unsigned short* eow3  = (unsigned short*)(r4 + 6291456);   // dead after p1<3>
  unsigned short* PHIb  = (unsigned short*)r4;
  unsigned short* wall  = (unsigned short*)(r4 + 6291456);   // 768*9216 bf16 = 14.2 MB
  unsigned short* PtG   = (unsigned short*)A2buf;

  const dim3 GBIG(128, 6);  // m-fast

  // 1. fused enc_o prep + fused qpool (Va/coW1 dots inside)
  bfprep_dot_kernel<<<NTOK_O / 4, 256, 0, stream>>>(enc_o, att_W3, att_W1_w, att_W1_b,
                                                    att_W2_w, att_W2_b, eobf, eow3,
                                                    s1o, s2o, NTOK_O);
  qpool2_kernel<<<256, 256, 0, stream>>>(enc_q, Va_w, Va_b, co_W1_w, co_W1_b,
                                         qm, qco1, Qpool);

  // 2. p1<3> (uses eow3), then wconv_all (overwrites eow3 region), then p2<3>
  p1_kernel<3><<<768, 256, 0, stream>>>(eobf, eow3, s1o, s2o, om, PtG);
  {
    WcAllArgs wa{};
    wa.src[0] = Wc_self_w; wa.src[1] = Wc_w;        wa.src[2] = Wc_w + HH;
    wa.src[3] = Wg_w;      wa.src[4] = Wg_w + HH;
    wa.src[5] = Wp_w;      wa.src[6] = Wp_w + HH;   wa.src[7] = Wp_w + 2 * HH;
    wa.src[8] = Wf_w;      wa.src[9] = Wf_w + HH;   wa.src[10] = Wf_w + 2 * HH;
    wa.src[11] = Wf_w + 3 * HH;
    int bases[12] = {0, 768, 1536, 2304, 3072, 3840, 4608, 5376, 6144, 6912, 7680, 8448};
    for (int i = 0; i < 12; ++i) wa.basecol[i] = bases[i];
    wa.dst = wall;
    wconv_all_kernel<<<dim3(144, 12), 256, 0, stream>>>(wa);
  }
  p2_kernel<3><<<dim3(4, 256), 256, 0, stream>>>(eobf, PtG, eobf, nullptr, X1, X2);

  // 3. OCK = tanh([o1 | 3o1-CS | o1*CS] @ Wc + (Wc_self_b + 3*Wc_b))
  {
    MMArgs g{};
    g.a[0] = eobf; g.a[1] = X1; g.a[2] = X2;
    g.K = 2304; g.wt = wall + 0;
    g.bias = Wc_self_b; g.bias2 = Wc_b; g.outb = OCKb;
    mfma_gemm_kernel<EP_TANH><<<GBIG, 512, 0, stream>>>(g);
  }

  // 4. Qg (f32)
  {
    GemmArgs g{};
    g.a[0] = Qpool; g.w[0] = Wg_w + 2 * HH;
    g.nchunks = 1; g.bias = Wg_b; g.out = Qg;
    gemm_store_kernel<<<dim3(12, 4), 256, 0, stream>>>(g);
  }

  // 5. merged = G*o1 + (1-G)*OCK
  {
    MMArgs g{};
    g.a[0] = eobf; g.a[1] = OCKb;
    g.K = 1536; g.wt = wall + 2304; g.bias = nullptr;
    g.aux0 = eobf; g.aux1 = OCKb; g.aux2 = Qg; g.outb = MRGb;
    mfma_gemm_kernel<EP_MERGE><<<GBIG, 512, 0, stream>>>(g);
  }

  // 6. co-attention: poaa2 (A2 + ms2 fused)
  poaa2_kernel<<<dim3(2, 256), 256, 0, stream>>>(enc_q, MRGb, qco1, co_W2_w, co_W2_b,
                                                 qm, om, co_W3, PLOb, PHIb);

  // 7. OPK = relu([merged | PLO | PHI] @ Wp + b)
  {
    MMArgs g{};
    g.a[0] = MRGb; g.a[1] = PLOb; g.a[2] = PHIb;
    g.K = 2304; g.wt = wall + 3840; g.bias = Wp_b; g.outb = OPKb;
    mfma_gemm_kernel<EP_RELU><<<GBIG, 512, 0, stream>>>(g);
  }

  // 8. self-attention
  opkprep_kernel<<<NTOK_O / 4, 256, 0, stream>>>(OPKb, sa_W3, sa_W1_w, sa_W1_b,
                                                 sa_W2_w, sa_W2_b, opkw3, sa1, sa2, NTOK_O);
  p1_kernel<1><<<256, 256, 0, stream>>>(OPKb, opkw3, sa1, sa2, om, PtG);
  p2_kernel<1><<<dim3(4, 256), 256, 0, stream>>>(OPKb, PtG, OPKb, OSKb, X3, X4);

  // 9. out = max_lo relu([OPK | OSK | OPK-OSK | OPK*OSK] @ Wf + b)
  {
    MMArgs g{};
    g.a[0] = OPKb; g.a[1] = OSKb; g.a[2] = X3; g.a[3] = X4;
    g.K = 3072; g.wt = wall + 6144; g.bias = Wf_b; g.outf = out;
    mfma_gemm_kernel<EP_RELU_MAX><<<GBIG, 512, 0, stream>>>(g);
  }
}

// Round 19
// 569.726 us; speedup vs baseline: 1.0998x; 1.0519x over previous
//
#include <hip/hip_runtime.h>
#include <math.h>

// OptionCompareCell: B=64,C=4,LO=64,LQ=128,H=768
// Round 19 (on top of confirmed-best r16/r18 = 599us):
//   Algebraic K-reduction of the final GEMM:
//     [OPK|OSK|OPK-OSK|OPK*OSK]@[W1;W2;W3;W4]
//       = OPK@(W1+W3) + OSK@(W2-W3) + (OPK*OSK)@W4        (exact algebra)
//   -> GEMM-9 K: 3072 -> 2304 (96 -> 72 barrier steps), X3 never written,
//      wconv_all combines W1+W3 / W2-W3 in f32 before the bf16 rounding,
//      KSTR 9216 -> 8448 (11 slices). All else identical to round 18.

#define NEGC (-10000.0f)
constexpr int HD = 768;
constexpr int KSTR = 8448;   // combined weight K-stride (11 x 768)

constexpr int EP_TANH = 1;
constexpr int EP_MERGE = 2;
constexpr int EP_RELU = 3;
constexpr int EP_RELU_MAX = 4;

typedef __attribute__((ext_vector_type(8))) short bf16x8;
typedef __attribute__((ext_vector_type(8))) unsigned short u16x8;
typedef __attribute__((ext_vector_type(4))) unsigned short u16x4;
typedef __attribute__((ext_vector_type(4))) float f32x4;

__device__ inline void st8(float* dst, float4 a0, float4 a1) {
  dst[0] = a0.x; dst[1] = a0.y; dst[2] = a0.z; dst[3] = a0.w;
  dst[4] = a1.x; dst[5] = a1.y; dst[6] = a1.z; dst[7] = a1.w;
}

__device__ inline unsigned short f2bf(float x) {
  unsigned int u = __float_as_uint(x);
  u += 0x7fffu + ((u >> 16) & 1u);
  return (unsigned short)(u >> 16);
}

__device__ inline float bf2f(unsigned short u) {
  return __uint_as_float(((unsigned int)u) << 16);
}

__device__ inline u16x8 pack8(float4 a, float4 b) {
  u16x8 r;
  r[0] = f2bf(a.x); r[1] = f2bf(a.y); r[2] = f2bf(a.z); r[3] = f2bf(a.w);
  r[4] = f2bf(b.x); r[5] = f2bf(b.y); r[6] = f2bf(b.z); r[7] = f2bf(b.w);
  return r;
}

__device__ inline u16x4 pack4(float4 a) {
  u16x4 r;
  r[0] = f2bf(a.x); r[1] = f2bf(a.y); r[2] = f2bf(a.z); r[3] = f2bf(a.w);
  return r;
}

__device__ inline void gload_lds16(const unsigned short* src, unsigned short* dst) {
  __builtin_amdgcn_global_load_lds(
      (const __attribute__((address_space(1))) void*)src,
      (__attribute__((address_space(3))) void*)dst, 16, 0, 0);
}

// ---------------- fused enc_o prep: eobf, eow3, s1o, s2o in one pass ----------------
__global__ __launch_bounds__(256)
void bfprep_dot_kernel(const float* __restrict__ x, const float* __restrict__ w3,
                       const float* __restrict__ w1, const float* __restrict__ b1,
                       const float* __restrict__ w2, const float* __restrict__ b2,
                       unsigned short* __restrict__ xbf, unsigned short* __restrict__ xw3,
                       float* __restrict__ o1, float* __restrict__ o2, int ntok) {
  int tok = blockIdx.x * 4 + (threadIdx.x >> 6);
  int lane = threadIdx.x & 63;
  if (tok >= ntok) return;
  const float* xp = x + (size_t)tok * HD;
  unsigned short* xb = xbf + (size_t)tok * HD;
  unsigned short* xw = xw3 + (size_t)tok * HD;
  float s1 = 0.f, s2 = 0.f;
#pragma unroll
  for (int i = 0; i < 3; ++i) {
    int c = (lane + (i << 6)) << 2;
    float4 xv = *(const float4*)(xp + c);
    float4 w3v = *(const float4*)(w3 + c);
    float4 wa = *(const float4*)(w1 + c);
    float4 wb = *(const float4*)(w2 + c);
    s1 = fmaf(xv.x, wa.x, s1); s1 = fmaf(xv.y, wa.y, s1);
    s1 = fmaf(xv.z, wa.z, s1); s1 = fmaf(xv.w, wa.w, s1);
    s2 = fmaf(xv.x, wb.x, s2); s2 = fmaf(xv.y, wb.y, s2);
    s2 = fmaf(xv.z, wb.z, s2); s2 = fmaf(xv.w, wb.w, s2);
    *(u16x4*)(xb + c) = pack4(xv);
    float4 sv;
    sv.x = xv.x * w3v.x; sv.y = xv.y * w3v.y; sv.z = xv.z * w3v.z; sv.w = xv.w * w3v.w;
    *(u16x4*)(xw + c) = pack4(sv);
  }
#pragma unroll
  for (int off = 32; off; off >>= 1) {
    s1 += __shfl_xor(s1, off);
    s2 += __shfl_xor(s2, off);
  }
  if (lane == 0) { o1[tok] = s1 + b1[0]; o2[tok] = s2 + b2[0]; }
}

// ---------------- fused OPK prep: opkw3, sa1, sa2 in one pass ----------------
__global__ __launch_bounds__(256)
void opkprep_kernel(const unsigned short* __restrict__ x, const float* __restrict__ w3,
                    const float* __restrict__ w1, const float* __restrict__ b1,
                    const float* __restrict__ w2, const float* __restrict__ b2,
                    unsigned short* __restrict__ xw3,
                    float* __restrict__ o1, float* __restrict__ o2, int ntok) {
  int tok = blockIdx.x * 4 + (threadIdx.x >> 6);
  int lane = threadIdx.x & 63;
  if (tok >= ntok) return;
  const unsigned short* xp = x + (size_t)tok * HD;
  unsigned short* xw = xw3 + (size_t)tok * HD;
  float s1 = 0.f, s2 = 0.f;
#pragma unroll
  for (int i = 0; i < 3; ++i) {
    int c = (lane + (i << 6)) << 2;
    u16x4 xv = *(const u16x4*)(xp + c);
    float x0 = bf2f(xv[0]), x1 = bf2f(xv[1]), x2 = bf2f(xv[2]), x3 = bf2f(xv[3]);
    float4 w3v = *(const float4*)(w3 + c);
    float4 wa = *(const float4*)(w1 + c);
    float4 wb = *(const float4*)(w2 + c);
    s1 = fmaf(x0, wa.x, s1); s1 = fmaf(x1, wa.y, s1);
    s1 = fmaf(x2, wa.z, s1); s1 = fmaf(x3, wa.w, s1);
    s2 = fmaf(x0, wb.x, s2); s2 = fmaf(x1, wb.y, s2);
    s2 = fmaf(x2, wb.z, s2); s2 = fmaf(x3, wb.w, s2);
    u16x4 sv;
    sv[0] = f2bf(x0 * w3v.x); sv[1] = f2bf(x1 * w3v.y);
    sv[2] = f2bf(x2 * w3v.z); sv[3] = f2bf(x3 * w3v.w);
    *(u16x4*)(xw + c) = sv;
  }
#pragma unroll
  for (int off = 32; off; off >>= 1) {
    s1 += __shfl_xor(s1, off);
    s2 += __shfl_xor(s2, off);
  }
  if (lane == 0) { o1[tok] = s1 + b1[0]; o2[tok] = s2 + b2[0]; }
}

// ---- qpool2: per bc, fused Va/co_W1 dots + masked softmax + pooled Q ----
__global__ __launch_bounds__(256)
void qpool2_kernel(const float* __restrict__ q,
                   const float* __restrict__ Va_w, const float* __restrict__ Va_b,
                   const float* __restrict__ coW1_w, const float* __restrict__ coW1_b,
                   const int* __restrict__ qm,
                   float* __restrict__ qco1, float* __restrict__ Q) {
  __shared__ float qa_s[128];
  __shared__ float wgt[128];
  __shared__ float wred[4];
  const int t = threadIdx.x, bc = blockIdx.x;
  const int lane = t & 63, wv = t >> 6;
  const float* qb = q + (size_t)bc * (128 * HD);
  for (int it = 0; it < 32; ++it) {
    const int tl = it * 4 + wv;
    const float* xp = qb + (size_t)tl * HD;
    float s1 = 0.f, s2 = 0.f;
#pragma unroll
    for (int i = 0; i < 3; ++i) {
      int c = (lane + (i << 6)) << 2;
      float4 xv = *(const float4*)(xp + c);
      float4 wa = *(const float4*)(Va_w + c);
      float4 wb = *(const float4*)(coW1_w + c);
      s1 = fmaf(xv.x, wa.x, s1); s1 = fmaf(xv.y, wa.y, s1);
      s1 = fmaf(xv.z, wa.z, s1); s1 = fmaf(xv.w, wa.w, s1);
      s2 = fmaf(xv.x, wb.x, s2); s2 = fmaf(xv.y, wb.y, s2);
      s2 = fmaf(xv.z, wb.z, s2); s2 = fmaf(xv.w, wb.w, s2);
    }
#pragma unroll
    for (int off = 32; off; off >>= 1) {
      s1 += __shfl_xor(s1, off);
      s2 += __shfl_xor(s2, off);
    }
    if (lane == 0) {
      qa_s[tl] = s1 + Va_b[0];
      qco1[bc * 128 + tl] = s2 + coW1_b[0];
    }
  }
  __syncthreads();
  const int* qmp = qm + bc * 128;
  float v = -1e30f;
  if (t < 128) v = qa_s[t] + (1.f - (float)qmp[t]) * NEGC;
  float m = v;
#pragma unroll
  for (int off = 32; off; off >>= 1) m = fmaxf(m, __shfl_xor(m, off));
  if ((t & 63) == 0) wred[t >> 6] = m;
  __syncthreads();
  float gm = fmaxf(fmaxf(wred[0], wred[1]), fmaxf(wred[2], wred[3]));
  float e = (t < 128) ? expf(v - gm) : 0.f;
  float s = e;
#pragma unroll
  for (int off = 32; off; off >>= 1) s += __shfl_xor(s, off);
  __syncthreads();
  if ((t & 63) == 0) wred[t >> 6] = s;
  __syncthreads();
  float tot = wred[0] + wred[1] + wred[2] + wred[3];
  if (t < 128) wgt[t] = e / tot;
  __syncthreads();
  float* Qp = Q + (size_t)bc * HD;
  for (int d = t; d < HD; d += 256) {
    float acc = 0.f;
    for (int l = 0; l < 128; ++l) acc = fmaf(wgt[l], qb[(size_t)l * HD + d], acc);
    Qp[d] = acc;
  }
}

// ---------------- P1: S = U . Vw3^T (MFMA), softmax over u, write Pt[v][u] bf16 ----------------
template<int NJ>
__global__ __launch_bounds__(256)
void p1_kernel(const unsigned short* __restrict__ Xbf, const unsigned short* __restrict__ Xw3,
               const float* __restrict__ s1g, const float* __restrict__ s2g,
               const int* __restrict__ maskg, unsigned short* __restrict__ PtG) {
  __shared__ __align__(16) unsigned short Ua[64 * 136];
  __shared__ __align__(16) unsigned short Vb[64 * 136];
  __shared__ float Sbuf[64][66];
  __shared__ float red[4][64];
  const int t = threadIdx.x;
  int ubc, vbc;
  if (NJ == 1) {
    ubc = vbc = blockIdx.x;
  } else {
    const int b = blockIdx.x / 12, pr = blockIdx.x % 12;
    const int i = pr / 3, jj = pr % 3;
    const int j = jj + (jj >= i ? 1 : 0);
    vbc = (b << 2) + i; ubc = (b << 2) + j;
  }
  const unsigned short* U = Xbf + (size_t)ubc * (64 * HD);
  const unsigned short* V = Xw3 + (size_t)vbc * (64 * HD);
  const int w = t >> 6, lane = t & 63, l15 = lane & 15, l4 = lane >> 4;
  const int srow = t >> 2, scol = (t & 3) << 5;
  f32x4 acc[4] = {};
  for (int k0 = 0; k0 < HD; k0 += 128) {
    const unsigned short* up = U + (size_t)srow * HD + k0 + scol;
    const unsigned short* vp = V + (size_t)srow * HD + k0 + scol;
    unsigned short* ua = &Ua[srow * 136 + scol];
    unsigned short* vb = &Vb[srow * 136 + scol];
#pragma unroll
    for (int z = 0; z < 4; ++z) {
      *(u16x8*)(ua + z * 8) = *(const u16x8*)(up + z * 8);
      *(u16x8*)(vb + z * 8) = *(const u16x8*)(vp + z * 8);
    }
    __syncthreads();
#pragma unroll
    for (int ks = 0; ks < 4; ++ks) {
      bf16x8 af = *(const bf16x8*)(&Ua[(w * 16 + l15) * 136 + ks * 32 + l4 * 8]);
#pragma unroll
      for (int n = 0; n < 4; ++n) {
        bf16x8 bf = *(const bf16x8*)(&Vb[(n * 16 + l15) * 136 + ks * 32 + l4 * 8]);
        acc[n] = __builtin_amdgcn_mfma_f32_16x16x32_bf16(af, bf, acc[n], 0, 0, 0);
      }
    }
    __syncthreads();
  }
  {
    float s1v[4];
#pragma unroll
    for (int r = 0; r < 4; ++r) {
      int u = w * 16 + l4 * 4 + r;
      s1v[r] = s1g[ubc * 64 + u] + (1.f - (float)maskg[ubc * 64 + u]) * NEGC;
    }
#pragma unroll
    for (int n = 0; n < 4; ++n) {
      int v = n * 16 + l15;
      float s2v = s2g[vbc * 64 + v] + (1.f - (float)maskg[vbc * 64 + v]) * NEGC;
#pragma unroll
      for (int r = 0; r < 4; ++r)
        Sbuf[w * 16 + l4 * 4 + r][v] = acc[n][r] + s1v[r] + s2v;
    }
  }
  __syncthreads();
  {
    const int v = t & 63, part = t >> 6;
    float m = -1e30f;
#pragma unroll
    for (int z = 0; z < 16; ++z) m = fmaxf(m, Sbuf[part * 16 + z][v]);
    red[part][v] = m;
    __syncthreads();
    float gm = fmaxf(fmaxf(red[0][v], red[1][v]), fmaxf(red[2][v], red[3][v]));
    float s = 0.f;
#pragma unroll
    for (int z = 0; z < 16; ++z) {
      float e = expf(Sbuf[part * 16 + z][v] - gm);
      Sbuf[part * 16 + z][v] = e;
      s += e;
    }
    __syncthreads();
    red[part][v] = s;
    __syncthreads();
    float cinv = 1.f / (red[0][v] + red[1][v] + red[2][v] + red[3][v]);
    unsigned short* pt = PtG + (size_t)blockIdx.x * 4096 + v * 64 + part * 16;
#pragma unroll
    for (int z = 0; z < 16; ++z) pt[z] = f2bf(Sbuf[part * 16 + z][v] * cinv);
  }
}

// ---- P2: ctx = sum_j Pt_j . U_j ; fused epilogue: NJ=3 -> X1,X2 ; NJ=1 -> OSK,X4 ----
template<int NJ>
__global__ __launch_bounds__(256)
void p2_kernel(const unsigned short* __restrict__ Xbf, const unsigned short* __restrict__ PtG,
               const unsigned short* __restrict__ Oi,
               unsigned short* __restrict__ osk,
               unsigned short* __restrict__ y1, unsigned short* __restrict__ y2) {
  __shared__ __align__(16) unsigned short Pts[NJ][64 * 72];
  __shared__ __align__(16) unsigned short U2[64 * 192];
  const int t = threadIdx.x;
  const int dq = blockIdx.x, bc = blockIdx.y;
  const int d0 = dq * 192;
  const int b = bc >> 2, i = bc & 3;
  const int w = t >> 6, lane = t & 63, l15 = lane & 15, l4 = lane >> 4;
  {
    const int v = t >> 2, cs = (t & 3) << 4;
#pragma unroll
    for (int jj = 0; jj < NJ; ++jj) {
      size_t src = (NJ == 1 ? (size_t)bc : (size_t)(b * 12 + i * 3 + jj)) * 4096 + v * 64 + cs;
      *(u16x8*)(&Pts[jj][v * 72 + cs]) = *(const u16x8*)(PtG + src);
      *(u16x8*)(&Pts[jj][v * 72 + cs + 8]) = *(const u16x8*)(PtG + src + 8);
    }
  }
  f32x4 acc[4][3] = {};
  const int su = t >> 2, sc0 = (t & 3) * 48;
  const int sswz = ((su >> 3) & 3) << 5;
  for (int jj = 0; jj < NJ; ++jj) {
    const int ubc = (NJ == 1) ? bc : ((b << 2) + (jj + (jj >= i ? 1 : 0)));
    __syncthreads();
    {
      const unsigned short* up = Xbf + (size_t)ubc * (64 * HD) + (size_t)su * HD + d0 + sc0;
#pragma unroll
      for (int it = 0; it < 6; ++it) {
        u16x8 vdat = *(const u16x8*)(up + it * 8);
        *(u16x8*)((char*)U2 + ((su * 384 + (sc0 + it * 8) * 2) ^ sswz)) = vdat;
      }
    }
    __syncthreads();
    const unsigned short* ptj = &Pts[jj][0];
#pragma unroll
    for (int ks = 0; ks < 2; ++ks) {
      bf16x8 bfr[3];
#pragma unroll
      for (int n = 0; n < 3; ++n) {
        const int col = (w * 3 + n) * 16 + l15;
#pragma unroll
        for (int e = 0; e < 8; ++e) {
          const int uk = ks * 32 + l4 * 8 + e;
          const int byte = (uk * 384 + col * 2) ^ (((uk >> 3) & 3) << 5);
          bfr[n][e] = *(const short*)((const char*)U2 + byte);
        }
      }
#pragma unroll
      for (int m = 0; m < 4; ++m) {
        bf16x8 af = *(const bf16x8*)(ptj + (m * 16 + l15) * 72 + ks * 32 + l4 * 8);
#pragma unroll
        for (int n = 0; n < 3; ++n)
          acc[m][n] = __builtin_amdgcn_mfma_f32_16x16x32_bf16(af, bfr[n], acc[m][n], 0, 0, 0);
      }
    }
  }
  const unsigned short* oip = Oi + (size_t)bc * (64 * HD);
  const size_t obase = (size_t)bc * (64 * HD);
#pragma unroll
  for (int m = 0; m < 4; ++m)
#pragma unroll
    for (int n = 0; n < 3; ++n) {
      const int d = d0 + (w * 3 + n) * 16 + l15;
#pragma unroll
      for (int r = 0; r < 4; ++r) {
        const int v = m * 16 + l4 * 4 + r;
        const size_t idx = obase + (size_t)v * HD + d;
        const float cs = acc[m][n][r];
        const float oi = bf2f(oip[(size_t)v * HD + d]);
        if (NJ == 3) {
          y1[idx] = f2bf(fmaf(3.f, oi, -cs));
          y2[idx] = f2bf(oi * cs);
        } else {
          osk[idx] = f2bf(cs);
          y2[idx] = f2bf(oi * cs);   // X4 only; X3 eliminated by weight folding
        }
      }
    }
}

// ---- POAA fused with A2 + ms2 (computed during Bm staging) ----
__global__ __launch_bounds__(256)
void poaa2_kernel(const float* __restrict__ qin, const unsigned short* __restrict__ mergedb,
                  const float* __restrict__ qco1,
                  const float* __restrict__ coW2_w, const float* __restrict__ coW2_b,
                  const int* __restrict__ qm, const int* __restrict__ om,
                  const float* __restrict__ w3,
                  unsigned short* __restrict__ PLO, unsigned short* __restrict__ PHI) {
  __shared__ __align__(16) char smem[77312];
  __shared__ float red[4][64];
  __shared__ float rowm[128], rowfac[128];
  __shared__ float colfac[64];
  __shared__ float ms2_s[64];
  __shared__ float gmax_s;
  float* T = (float*)smem;                                   // [128][65] f32
  unsigned short* Aq = (unsigned short*)smem;                 // [128][72] (phase0)
  unsigned short* Bm = (unsigned short*)(smem + 18432);       // [64][72]  (phase0)
  unsigned short* Tt = (unsigned short*)(smem + 33280);       // [64][136]
  unsigned short* Tft = (unsigned short*)(smem + 50688);      // [64][136]
  unsigned short* M2bf = (unsigned short*)(smem + 68096);     // [64][72]
  unsigned short* Qc = (unsigned short*)smem;                 // [128][72] (chunk phase)
  unsigned short* Mc = (unsigned short*)(smem + 18432);       // [64][72]

  const int t = threadIdx.x, dqh = blockIdx.x, bc = blockIdx.y;
  const int w = t >> 6, lane = t & 63, l15 = lane & 15, l4 = lane >> 4;
  const float* qp = qin + (size_t)bc * (128 * HD);
  const unsigned short* mp = mergedb + (size_t)bc * (64 * HD);
  const float* qc = qco1 + bc * 128;
  const int* qmp = qm + bc * 128;
  const int* omp = om + bc * 64;

  // ---- phase 0: A2 = (q*w3).merged^T via MFMA ; ms2 dot rides the Bm staging ----
  {
    const int arow = t >> 1, acs = (t & 1) << 5;
    const int brow = t >> 2, bcs = (t & 3) << 4;
    f32x4 acc[2][4] = {};
    float msacc = 0.f;
    for (int k0 = 0; k0 < HD; k0 += 64) {
      {
        const float* p = qp + (size_t)arow * HD + k0 + acs;
        const float* wp = w3 + k0 + acs;
        unsigned short* dst = &Aq[arow * 72 + acs];
#pragma unroll
        for (int z = 0; z < 4; ++z) {
          float4 a = *(const float4*)(p + z * 8);
          float4 b = *(const float4*)(p + z * 8 + 4);
          float4 wa = *(const float4*)(wp + z * 8);
          float4 wb = *(const float4*)(wp + z * 8 + 4);
          a.x *= wa.x; a.y *= wa.y; a.z *= wa.z; a.w *= wa.w;
          b.x *= wb.x; b.y *= wb.y; b.z *= wb.z; b.w *= wb.w;
          *(u16x8*)(dst + z * 8) = pack8(a, b);
        }
      }
      {
        const unsigned short* p = mp + (size_t)brow * HD + k0 + bcs;
        unsigned short* dst = &Bm[brow * 72 + bcs];
        u16x8 v0 = *(const u16x8*)(p);
        u16x8 v1 = *(const u16x8*)(p + 8);
        *(u16x8*)(dst) = v0;
        *(u16x8*)(dst + 8) = v1;
        const float* wp = coW2_w + k0 + bcs;
        float4 wa = *(const float4*)(wp);
        float4 wb = *(const float4*)(wp + 4);
        float4 wc = *(const float4*)(wp + 8);
        float4 wd = *(const float4*)(wp + 12);
        msacc = fmaf(bf2f(v0[0]), wa.x, msacc); msacc = fmaf(bf2f(v0[1]), wa.y, msacc);
        msacc = fmaf(bf2f(v0[2]), wa.z, msacc); msacc = fmaf(bf2f(v0[3]), wa.w, msacc);
        msacc = fmaf(bf2f(v0[4]), wb.x, msacc); msacc = fmaf(bf2f(v0[5]), wb.y, msacc);
        msacc = fmaf(bf2f(v0[6]), wb.z, msacc); msacc = fmaf(bf2f(v0[7]), wb.w, msacc);
        msacc = fmaf(bf2f(v1[0]), wc.x, msacc); msacc = fmaf(bf2f(v1[1]), wc.y, msacc);
        msacc = fmaf(bf2f(v1[2]), wc.z, msacc); msacc = fmaf(bf2f(v1[3]), wc.w, msacc);
        msacc = fmaf(bf2f(v1[4]), wd.x, msacc); msacc = fmaf(bf2f(v1[5]), wd.y, msacc);
        msacc = fmaf(bf2f(v1[6]), wd.z, msacc); msacc = fmaf(bf2f(v1[7]), wd.w, msacc);
      }
      __syncthreads();
#pragma unroll
      for (int ks = 0; ks < 2; ++ks) {
        bf16x8 af[2], bf[4];
#pragma unroll
        for (int m = 0; m < 2; ++m)
          af[m] = *(const bf16x8*)(&Aq[(w * 32 + m * 16 + l15) * 72 + ks * 32 + l4 * 8]);
#pragma unroll
        for (int n = 0; n < 4; ++n)
          bf[n] = *(const bf16x8*)(&Bm[(n * 16 + l15) * 72 + ks * 32 + l4 * 8]);
#pragma unroll
        for (int m = 0; m < 2; ++m)
#pragma unroll
          for (int n = 0; n < 4; ++n)
            acc[m][n] = __builtin_amdgcn_mfma_f32_16x16x32_bf16(af[m], bf[n], acc[m][n], 0, 0, 0);
      }
      __syncthreads();
    }
    msacc += __shfl_xor(msacc, 1);
    msacc += __shfl_xor(msacc, 2);
    if ((t & 3) == 0) ms2_s[brow] = msacc + coW2_b[0];
    __syncthreads();
#pragma unroll
    for (int n = 0; n < 4; ++n) {
      const int v = n * 16 + l15;
      const float ct = ms2_s[v] + (1.f - (float)omp[v]) * NEGC;
#pragma unroll
      for (int m = 0; m < 2; ++m)
#pragma unroll
        for (int r = 0; r < 4; ++r) {
          const int qrow = w * 32 + m * 16 + l4 * 4 + r;
          const float rt = qc[qrow] + (1.f - (float)qmp[qrow]) * NEGC;
          T[qrow * 65 + v] = acc[m][n][r] + rt + ct;
        }
    }
  }
  __syncthreads();
  // ---- stats ----
  {
    int qrow = t >> 1, h = t & 1;
    float m = -1e30f;
    for (int v = h * 32; v < h * 32 + 32; ++v) m = fmaxf(m, T[qrow * 65 + v]);
    m = fmaxf(m, __shfl_xor(m, 1));
    float s = 0.f;
    for (int v = h * 32; v < h * 32 + 32; ++v) s += expf(T[qrow * 65 + v] - m);
    s += __shfl_xor(s, 1);
    if (h == 0) { rowm[qrow] = m; rowfac[qrow] = s; }
  }
  float colm_loc = 0.f;
  {
    int v = t & 63, part = t >> 6;
    float m = -1e30f;
    for (int qq = part * 32; qq < part * 32 + 32; ++qq) m = fmaxf(m, T[qq * 65 + v]);
    red[part][v] = m;
    __syncthreads();
    float cm = fmaxf(fmaxf(red[0][v], red[1][v]), fmaxf(red[2][v], red[3][v]));
    float s = 0.f;
    for (int qq = part * 32; qq < part * 32 + 32; ++qq) s += expf(T[qq * 65 + v] - cm);
    __syncthreads();
    red[part][v] = s;
    __syncthreads();
    if (part == 0) { colm_loc = cm; colfac[v] = red[0][v] + red[1][v] + red[2][v] + red[3][v]; }
  }
  __syncthreads();
  if (t < 64) {
    float m = fmaxf(rowm[t], rowm[t + 64]);
#pragma unroll
    for (int off = 32; off; off >>= 1) m = fmaxf(m, __shfl_xor(m, off));
    if (t == 0) gmax_s = m;
  }
  __syncthreads();
  const float gmax = gmax_s;
  if (t < 128) rowfac[t] = expf(fminf(gmax - rowm[t], 60.f)) / rowfac[t];
  if (t < 64) colfac[t] = expf(fminf(gmax - colm_loc, 60.f)) / colfac[t];
  __syncthreads();
  {
    const int o = t >> 2, qs = (t & 3) << 5;
    for (int z = 0; z < 32; ++z) {
      const int qq = qs + z;
      float e = expf(T[qq * 65 + o] - gmax);
      Tt[o * 136 + qq] = f2bf(e);
      Tft[o * 136 + qq] = f2bf(e * rowfac[qq]);
    }
  }
  __syncthreads();
  {
    f32x4 m2acc[4] = {};
#pragma unroll
    for (int ks = 0; ks < 4; ++ks) {
      bf16x8 af = *(const bf16x8*)(&Tt[(w * 16 + l15) * 136 + ks * 32 + l4 * 8]);
#pragma unroll
      for (int n = 0; n < 4; ++n) {
        bf16x8 bf = *(const bf16x8*)(&Tft[(n * 16 + l15) * 136 + ks * 32 + l4 * 8]);
        m2acc[n] = __builtin_amdgcn_mfma_f32_16x16x32_bf16(af, bf, m2acc[n], 0, 0, 0);
      }
    }
#pragma unroll
    for (int n = 0; n < 4; ++n)
#pragma unroll
      for (int r = 0; r < 4; ++r) {
        const int o = w * 16 + l4 * 4 + r;
        M2bf[o * 72 + n * 16 + l15] = f2bf(colfac[o] * m2acc[n][r]);
      }
  }
  // ---- chunk phase (d-half dqh) ----
  const int dql = t >> 1, dqs = (t & 1) << 5;
  const int dml = t >> 2, dms = (t & 3) << 4;
  const int swq = ((dql >> 3) & 3) << 5;
  const int swm = ((dml >> 3) & 3) << 5;
  unsigned short* plo = PLO + (size_t)bc * (64 * HD);
  unsigned short* phi = PHI + (size_t)bc * (64 * HD);
  for (int dc = dqh * 6; dc < dqh * 6 + 6; ++dc) {
    const int d0 = dc * 64;
    __syncthreads();
    {
      const float* p = qp + (size_t)dql * HD + d0 + dqs;
#pragma unroll
      for (int z = 0; z < 4; ++z) {
        float4 a = *(const float4*)(p + z * 8);
        float4 b = *(const float4*)(p + z * 8 + 4);
        *(u16x8*)((char*)Qc + ((dql * 144 + (dqs + z * 8) * 2) ^ swq)) = pack8(a, b);
      }
    }
    {
      const unsigned short* p = mp + (size_t)dml * HD + d0 + dms;
      *(u16x8*)((char*)Mc + ((dml * 144 + dms * 2) ^ swm)) = *(const u16x8*)p;
      *(u16x8*)((char*)Mc + ((dml * 144 + (dms + 8) * 2) ^ swm)) = *(const u16x8*)(p + 8);
    }
    __syncthreads();
    const int col = w * 16 + l15;
    f32x4 lacc[4] = {};
#pragma unroll
    for (int ks = 0; ks < 4; ++ks) {
      bf16x8 bf;
#pragma unroll
      for (int e = 0; e < 8; ++e) {
        const int qq = ks * 32 + l4 * 8 + e;
        bf[e] = *(const short*)((const char*)Qc + ((qq * 144 + col * 2) ^ (((qq >> 3) & 3) << 5)));
      }
#pragma unroll
      for (int m = 0; m < 4; ++m) {
        bf16x8 af = *(const bf16x8*)(&Tt[(m * 16 + l15) * 136 + ks * 32 + l4 * 8]);
        lacc[m] = __builtin_amdgcn_mfma_f32_16x16x32_bf16(af, bf, lacc[m], 0, 0, 0);
      }
    }
    f32x4 pacc[4] = {};
#pragma unroll
    for (int ks = 0; ks < 2; ++ks) {
      bf16x8 bf;
#pragma unroll
      for (int e = 0; e < 8; ++e) {
        const int vv = ks * 32 + l4 * 8 + e;
        bf[e] = *(const short*)((const char*)Mc + ((vv * 144 + col * 2) ^ (((vv >> 3) & 3) << 5)));
      }
#pragma unroll
      for (int m = 0; m < 4; ++m) {
        bf16x8 af = *(const bf16x8*)(&M2bf[(m * 16 + l15) * 72 + ks * 32 + l4 * 8]);
        pacc[m] = __builtin_amdgcn_mfma_f32_16x16x32_bf16(af, bf, pacc[m], 0, 0, 0);
      }
    }
#pragma unroll
    for (int m = 0; m < 4; ++m)
#pragma unroll
      for (int r = 0; r < 4; ++r) {
        const int o = m * 16 + l4 * 4 + r;
        const int d = d0 + w * 16 + l15;
        plo[(size_t)o * HD + d] = f2bf(colfac[o] * lacc[m][r]);
        phi[(size_t)o * HD + d] = f2bf(pacc[m][r]);
      }
  }
}

// ---------------- small f32 GEMM (Qg only) ----------------
struct GemmArgs {
  const float* a[4];
  const float* w[4];
  int nchunks;
  const float* bias;
  float* out;
};

__global__ __launch_bounds__(256)
void gemm_store_kernel(GemmArgs g) {
  __shared__ float As[64][33];
  __shared__ float Ws[32][65];
  const int t = threadIdx.x;
  const int m0 = blockIdx.y << 6, n0 = blockIdx.x << 6;
  const int tr = t >> 4, tc = t & 15;
  float acc[4][4];
#pragma unroll
  for (int x = 0; x < 4; ++x)
#pragma unroll
    for (int y = 0; y < 4; ++y) acc[x][y] = 0.f;
  const int arow = t >> 2, acs = (t & 3) << 3;
  const int wrow = t >> 3, wcs = (t & 7) << 3;
  for (int c = 0; c < g.nchunks; ++c) {
    const float* Ap = g.a[c] + (size_t)(m0 + arow) * HD + acs;
    const float* Wp = g.w[c] + (size_t)wrow * HD + n0 + wcs;
    for (int k0 = 0; k0 < HD; k0 += 32) {
      float4 a0 = *(const float4*)(Ap + k0);
      float4 a1 = *(const float4*)(Ap + k0 + 4);
      st8(&As[arow][acs], a0, a1);
      float4 w0 = *(const float4*)(Wp + (size_t)k0 * HD);
      float4 w1 = *(const float4*)(Wp + (size_t)k0 * HD + 4);
      st8(&Ws[wrow][wcs], w0, w1);
      __syncthreads();
#pragma unroll
      for (int kk = 0; kk < 32; ++kk) {
        float av[4], bv[4];
#pragma unroll
        for (int x = 0; x < 4; ++x) av[x] = As[(tr << 2) + x][kk];
#pragma unroll
        for (int y = 0; y < 4; ++y) bv[y] = Ws[kk][(tc << 2) + y];
#pragma unroll
        for (int x = 0; x < 4; ++x)
#pragma unroll
          for (int y = 0; y < 4; ++y) acc[x][y] = fmaf(av[x], bv[y], acc[x][y]);
      }
      __syncthreads();
    }
  }
#pragma unroll
  for (int x = 0; x < 4; ++x) {
    const int r = m0 + (tr << 2) + x;
#pragma unroll
    for (int y = 0; y < 4; ++y) {
      const int n = n0 + (tc << 2) + y;
      g.out[(size_t)r * HD + n] = acc[x][y] + g.bias[n];
    }
  }
}

// ---- wconv_all: 11 weight slices -> wall[768][8448] bf16; optional srcB fold ----
struct WcAllArgs {
  const float* src[12];
  const float* srcB[12];
  float coefB[12];
  int basecol[12];
  unsigned short* dst;
};

__global__ __launch_bounds__(256)
void wconv_all_kernel(WcAllArgs g) {
  __shared__ float tile[64][65];
  const int slice = blockIdx.y;
  const float* src = g.src[slice];
  const float* srcB = g.srcB[slice];
  const float coef = g.coefB[slice];
  const int bi = blockIdx.x % 12, bj = blockIdx.x / 12;
  const int t = threadIdx.x;
  const int r = t >> 2, cseg = (t & 3) << 4;
  const size_t soff = (size_t)(bi * 64 + r) * HD + bj * 64 + cseg;
  const float* p = src + soff;
#pragma unroll
  for (int j = 0; j < 16; j += 4) {
    float4 v = *(const float4*)(p + j);
    if (srcB) {
      float4 vb = *(const float4*)(srcB + soff + j);
      v.x = fmaf(coef, vb.x, v.x); v.y = fmaf(coef, vb.y, v.y);
      v.z = fmaf(coef, vb.z, v.z); v.w = fmaf(coef, vb.w, v.w);
    }
    tile[r][cseg + j + 0] = v.x; tile[r][cseg + j + 1] = v.y;
    tile[r][cseg + j + 2] = v.z; tile[r][cseg + j + 3] = v.w;
  }
  __syncthreads();
  unsigned short* q = g.dst + (size_t)(bj * 64 + r) * KSTR + g.basecol[slice] + bi * 64 + cseg;
  u16x8 lo, hi;
#pragma unroll
  for (int j = 0; j < 8; ++j) lo[j] = f2bf(tile[cseg + j][r]);
#pragma unroll
  for (int j = 0; j < 8; ++j) hi[j] = f2bf(tile[cseg + 8 + j][r]);
  *(u16x8*)q = lo;
  *(u16x8*)(q + 8) = hi;
}

// ---- bf16 MFMA GEMM: 8-wave blocks, 3-deep two-barrier counted-vmcnt (r16) ----
struct MMArgs {
  const unsigned short* a[4];   // per-768-chunk bf16 sources (all mode-0)
  int K;
  const unsigned short* wt;     // wall + basecol, row stride KSTR
  const float* bias;
  const float* bias2;           // EP_TANH: bias + 3*bias2
  const unsigned short* aux0;   // o1 bf16  (EP_MERGE)
  const unsigned short* aux1;   // OCK bf16 (EP_MERGE)
  const float* aux2;            // Qg f32   (EP_MERGE)
  float* outf;                  // EP_RELU_MAX
  unsigned short* outb;         // others
};

template<int EP>
__global__ __launch_bounds__(512)
void mfma_gemm_kernel(MMArgs g) {
  __shared__ __align__(16) unsigned short As[3][128 * 32];
  __shared__ __align__(16) unsigned short Bs[3][128 * 32];
  const int t = threadIdx.x;
  const int lane = t & 63, w = t >> 6;       // 8 waves
  const int wr = w >> 2, wc = w & 3;          // 2 x 4 decomposition
  const int m0 = blockIdx.x << 7, n0 = blockIdx.y << 7;  // m-fast grid
  const int l15 = lane & 15, l4 = lane >> 4;
  f32x4 acc[4][2] = {};

  const int srow = w * 16 + (lane >> 2);
  const int gcol = (((lane & 3) ^ ((lane >> 3) & 3))) * 8;   // shorts
  const int rsw = (l15 >> 1) & 3;
  const int rcol = ((l4 ^ rsw)) * 8;                          // shorts

  const int nkt = g.K >> 5;

  auto issue = [&](int kt, int buf) {
    const int c = kt / 24;
    const int koff = (kt - c * 24) << 5;
    const unsigned short* ap = g.a[c] + (size_t)(m0 + srow) * HD + koff + gcol;
    const unsigned short* bp = g.wt + (size_t)(n0 + srow) * KSTR + (kt << 5) + gcol;
    gload_lds16(ap, &As[buf][w * 512]);
    gload_lds16(bp, &Bs[buf][w * 512]);
  };

  auto compute = [&](int kt, int buf, bool prefetch) {
    bf16x8 af[4], bfr[2];
#pragma unroll
    for (int mi = 0; mi < 4; ++mi)
      af[mi] = *(const bf16x8*)(&As[buf][(wr * 64 + mi * 16 + l15) * 32 + rcol]);
#pragma unroll
    for (int ni = 0; ni < 2; ++ni)
      bfr[ni] = *(const bf16x8*)(&Bs[buf][(wc * 32 + ni * 16 + l15) * 32 + rcol]);
    asm volatile("s_waitcnt lgkmcnt(0)" ::: "memory");  // my frags in regs
    __builtin_amdgcn_s_barrier();                        // everyone done reading buf
    if (prefetch) issue(kt + 3, buf);                    // safe to overwrite now
    __builtin_amdgcn_s_setprio(1);
#pragma unroll
    for (int mi = 0; mi < 4; ++mi)
#pragma unroll
      for (int ni = 0; ni < 2; ++ni)
        acc[mi][ni] = __builtin_amdgcn_mfma_f32_16x16x32_bf16(af[mi], bfr[ni], acc[mi][ni], 0, 0, 0);
    __builtin_amdgcn_s_setprio(0);
  };

  // prologue: 3 tiles in flight (6 loads/wave)
  issue(0, 0); issue(1, 1); issue(2, 2);
  int buf = 0;
  int kt = 0;
  for (; kt < nkt - 2; ++kt) {
    asm volatile("s_waitcnt vmcnt(4)" ::: "memory");
    __builtin_amdgcn_s_barrier();
    compute(kt, buf, kt + 3 < nkt);
    buf = (buf == 2) ? 0 : buf + 1;
  }
  asm volatile("s_waitcnt vmcnt(2)" ::: "memory");
  __builtin_amdgcn_s_barrier();
  compute(kt, buf, false);
  buf = (buf == 2) ? 0 : buf + 1;
  ++kt;
  asm volatile("s_waitcnt vmcnt(0)" ::: "memory");
  __builtin_amdgcn_s_barrier();
  compute(kt, buf, false);

  if (EP == EP_RELU_MAX) {
#pragma unroll
    for (int ni = 0; ni < 2; ++ni) {
      const int n = n0 + wc * 32 + ni * 16 + l15;
      const float b = g.bias[n];
      float m = 0.f;
#pragma unroll
      for (int mi = 0; mi < 4; ++mi)
#pragma unroll
        for (int r = 0; r < 4; ++r)
          m = fmaxf(m, acc[mi][ni][r] + b);
      m = fmaxf(m, 0.f);
      m = fmaxf(m, __shfl_xor(m, 16));
      m = fmaxf(m, __shfl_xor(m, 32));
      if (l4 == 0) g.outf[(size_t)((m0 >> 6) + wr) * HD + n] = m;
    }
  } else {
#pragma unroll
    for (int mi = 0; mi < 4; ++mi)
#pragma unroll
      for (int r = 0; r < 4; ++r) {
        const int row = m0 + wr * 64 + mi * 16 + l4 * 4 + r;
#pragma unroll
        for (int ni = 0; ni < 2; ++ni) {
          const int n = n0 + wc * 32 + ni * 16 + l15;
          const size_t oi = (size_t)row * HD + n;
          float v = acc[mi][ni][r];
          if (EP == EP_TANH) {
            g.outb[oi] = f2bf(tanhf(v + g.bias[n] + 3.f * g.bias2[n]));
          } else if (EP == EP_MERGE) {
            float gg = v + g.aux2[(size_t)(row >> 6) * HD + n];
            float sg = 1.f / (1.f + expf(-gg));
            float o1v = bf2f(g.aux0[oi]);
            float ock = bf2f(g.aux1[oi]);
            g.outb[oi] = f2bf(fmaf(sg, o1v - ock, ock));
          } else {  // EP_RELU
            g.outb[oi] = f2bf(fmaxf(v + g.bias[n], 0.f));
          }
        }
      }
  }
}

extern "C" void kernel_launch(void* const* d_in, const int* in_sizes, int n_in,
                              void* d_out, int out_size, void* d_ws, size_t ws_size,
                              hipStream_t stream) {
  const float* enc_o = (const float*)d_in[0];
  const float* enc_q = (const float*)d_in[1];
  const int* om = (const int*)d_in[2];
  const int* qm = (const int*)d_in[3];
  const float* att_W1_w = (const float*)d_in[4];
  const float* att_W1_b = (const float*)d_in[5];
  const float* att_W2_w = (const float*)d_in[6];
  const float* att_W2_b = (const float*)d_in[7];
  const float* att_W3 = (const float*)d_in[8];
  const float* Wc_self_w = (const float*)d_in[9];
  const float* Wc_self_b = (const float*)d_in[10];
  const float* Wc_w = (const float*)d_in[11];
  const float* Wc_b = (const float*)d_in[12];
  const float* Va_w = (const float*)d_in[13];
  const float* Va_b = (const float*)d_in[14];
  const float* Wg_w = (const float*)d_in[15];
  const float* Wg_b = (const float*)d_in[16];
  const float* co_W1_w = (const float*)d_in[17];
  const float* co_W1_b = (const float*)d_in[18];
  const float* co_W2_w = (const float*)d_in[19];
  const float* co_W2_b = (const float*)d_in[20];
  const float* co_W3 = (const float*)d_in[21];
  const float* Wp_w = (const float*)d_in[22];
  const float* Wp_b = (const float*)d_in[23];
  const float* sa_W1_w = (const float*)d_in[24];
  const float* sa_W1_b = (const float*)d_in[25];
  const float* sa_W2_w = (const float*)d_in[26];
  const float* sa_W2_b = (const float*)d_in[27];
  const float* sa_W3 = (const float*)d_in[28];
  const float* Wf_w = (const float*)d_in[29];
  const float* Wf_b = (const float*)d_in[30];
  float* out = (float*)d_out;

  const int NTOK_O = 16384;
  const int HH = 768 * 768;

  float* ws = (float*)d_ws;
  size_t off = 0;
  auto carve = [&](size_t n) { float* p = ws + off; off += n; return p; };
  float* s1o   = carve(16384);
  float* s2o   = carve(16384);
  float* qco1  = carve(32768);
  float* sa1   = carve(16384);
  float* sa2   = carve(16384);
  float* Qpool = carve(196608);
  float* Qg    = carve(196608);
  float* A2buf = carve(2097152);   // PtG only
  float* r1 = carve(12582912);   // [-- | X1] -> [OPKb | --]
  float* r2 = carve(12582912);   // [OCKb | X2] -> [PLOb | ..] -> opkw3
  float* r3 = carve(12582912);   // [MRGb | ..] -> [OSKb | X4]
  float* r4 = carve(12582912);   // [eobf | eow3] -> [PHIb | wall]
  if (ws_size < off * sizeof(float)) return;
  unsigned short* OPKb  = (unsigned short*)r1;
  unsigned short* X1    = (unsigned short*)(r1 + 6291456);
  unsigned short* OCKb  = (unsigned short*)r2;
  unsigned short* PLOb  = (unsigned short*)r2;
  unsigned short* opkw3 = (unsigned short*)r2;
  unsigned short* X2    = (unsigned short*)(r2 + 6291456);
  unsigned short* MRGb  = (unsigned short*)r3;
  unsigned short* OSKb  = (unsigned short*)r3;
  unsigned short* X4    = (unsigned short*)(r3 + 6291456);
  unsigned short* eobf  = (unsigned short*)r4;
  unsigned short* eow3  = (unsigned short*)(r4 + 6291456);   // dead after p1<3>
  unsigned short* PHIb  = (unsigned short*)r4;
  unsigned short* wall  = (unsigned short*)(r4 + 6291456);   // 768*8448 bf16 = 13.0 MB
  unsigned short* PtG   = (unsigned short*)A2buf;

  const dim3 GBIG(128, 6);  // m-fast

  // 1. fused enc_o prep + fused qpool (Va/coW1 dots inside)
  bfprep_dot_kernel<<<NTOK_O / 4, 256, 0, stream>>>(enc_o, att_W3, att_W1_w, att_W1_b,
                                                    att_W2_w, att_W2_b, eobf, eow3,
                                                    s1o, s2o, NTOK_O);
  qpool2_kernel<<<256, 256, 0, stream>>>(enc_q, Va_w, Va_b, co_W1_w, co_W1_b,
                                         qm, qco1, Qpool);

  // 2. p1<3> (uses eow3), then wconv_all (overwrites eow3 region), then p2<3>
  p1_kernel<3><<<768, 256, 0, stream>>>(eobf, eow3, s1o, s2o, om, PtG);
  {
    WcAllArgs wa{};
    // 11 slices; slots 8/9 fold Wf3 into Wf1/Wf2 (f32 add before bf16 rounding)
    wa.src[0] = Wc_self_w;    wa.src[1] = Wc_w;          wa.src[2] = Wc_w + HH;
    wa.src[3] = Wg_w;         wa.src[4] = Wg_w + HH;
    wa.src[5] = Wp_w;         wa.src[6] = Wp_w + HH;     wa.src[7] = Wp_w + 2 * HH;
    wa.src[8] = Wf_w;         wa.src[9] = Wf_w + HH;     wa.src[10] = Wf_w + 3 * HH;
    for (int i = 0; i < 12; ++i) { wa.srcB[i] = nullptr; wa.coefB[i] = 0.f; }
    wa.srcB[8] = Wf_w + 2 * HH; wa.coefB[8] = 1.f;    // Wf1 + Wf3
    wa.srcB[9] = Wf_w + 2 * HH; wa.coefB[9] = -1.f;   // Wf2 - Wf3
    int bases[12] = {0, 768, 1536, 2304, 3072, 3840, 4608, 5376, 6144, 6912, 7680, 0};
    for (int i = 0; i < 12; ++i) wa.basecol[i] = bases[i];
    wa.dst = wall;
    wconv_all_kernel<<<dim3(144, 11), 256, 0, stream>>>(wa);
  }
  p2_kernel<3><<<dim3(4, 256), 256, 0, stream>>>(eobf, PtG, eobf, nullptr, X1, X2);

  // 3. OCK = tanh([o1 | 3o1-CS | o1*CS] @ Wc + (Wc_self_b + 3*Wc_b))
  {
    MMArgs g{};
    g.a[0] = eobf; g.a[1] = X1; g.a[2] = X2;
    g.K = 2304; g.wt = wall + 0;
    g.bias = Wc_self_b; g.bias2 = Wc_b; g.outb = OCKb;
    mfma_gemm_kernel<EP_TANH><<<GBIG, 512, 0, stream>>>(g);
  }

  // 4. Qg (f32)
  {
    GemmArgs g{};
    g.a[0] = Qpool; g.w[0] = Wg_w + 2 * HH;
    g.nchunks = 1; g.bias = Wg_b; g.out = Qg;
    gemm_store_kernel<<<dim3(12, 4), 256, 0, stream>>>(g);
  }

  // 5. merged = G*o1 + (1-G)*OCK
  {
    MMArgs g{};
    g.a[0] = eobf; g.a[1] = OCKb;
    g.K = 1536; g.wt = wall + 2304; g.bias = nullptr;
    g.aux0 = eobf; g.aux1 = OCKb; g.aux2 = Qg; g.outb = MRGb;
    mfma_gemm_kernel<EP_MERGE><<<GBIG, 512, 0, stream>>>(g);
  }

  // 6. co-attention: poaa2 (A2 + ms2 fused)
  poaa2_kernel<<<dim3(2, 256), 256, 0, stream>>>(enc_q, MRGb, qco1, co_W2_w, co_W2_b,
                                                 qm, om, co_W3, PLOb, PHIb);

  // 7. OPK = relu([merged | PLO | PHI] @ Wp + b)
  {
    MMArgs g{};
    g.a[0] = MRGb; g.a[1] = PLOb; g.a[2] = PHIb;
    g.K = 2304; g.wt = wall + 3840; g.bias = Wp_b; g.outb = OPKb;
    mfma_gemm_kernel<EP_RELU><<<GBIG, 512, 0, stream>>>(g);
  }

  // 8. self-attention
  opkprep_kernel<<<NTOK_O / 4, 256, 0, stream>>>(OPKb, sa_W3, sa_W1_w, sa_W1_b,
                                                 sa_W2_w, sa_W2_b, opkw3, sa1, sa2, NTOK_O);
  p1_kernel<1><<<256, 256, 0, stream>>>(OPKb, opkw3, sa1, sa2, om, PtG);
  p2_kernel<1><<<dim3(4, 256), 256, 0, stream>>>(OPKb, PtG, OPKb, OSKb, nullptr, X4);

  // 9. out = max_lo relu( OPK@(Wf1+Wf3) + OSK@(Wf2-Wf3) + (OPK*OSK)@Wf4 + b )
  {
    MMArgs g{};
    g.a[0] = OPKb; g.a[1] = OSKb; g.a[2] = X4;
    g.K = 2304; g.wt = wall + 6144; g.bias = Wf_b; g.outf = out;
    mfma_gemm_kernel<EP_RELU_MAX><<<GBIG, 512, 0, stream>>>(g);
  }
}